// Round 1
// 628.127 us; speedup vs baseline: 1.2126x; 1.2126x over previous
//
#include <hip/hip_runtime.h>
#include <math.h>

#define B_ 16
#define L_ 256
#define S_ 100
#define LA_ 48
#define NA_ 32
#define E_ 64
#define D_ 768
#define H_ 12
#define NHID_ 1024
#define WIDX_ 102
#define EPSF 1e-12f

typedef __attribute__((ext_vector_type(8))) short s16x8;     // 8 bf16 (4 VGPRs) - MFMA A/B frag
typedef __attribute__((ext_vector_type(4))) float f32x4;     // MFMA C/D frag

// split x into bf16 hi + bf16 lo (RTNE), x ~= hi + lo to ~2^-17 rel
__device__ __forceinline__ void split_bf16(float x, unsigned short& h, unsigned short& l) {
  unsigned u = __float_as_uint(x);
  unsigned hr = u + 0x7FFFu + ((u >> 16) & 1u);
  h = (unsigned short)(hr >> 16);
  float r = x - __uint_as_float(hr & 0xFFFF0000u);
  unsigned u2 = __float_as_uint(r);
  unsigned lr = u2 + 0x7FFFu + ((u2 >> 16) & 1u);
  l = (unsigned short)(lr >> 16);
}

// ---------------- meta: per-b sb, sls, last ----------------
__global__ void k_meta(const int* __restrict__ idxs, const int* __restrict__ blen,
                       int* __restrict__ meta) {
  int b = blockIdx.x, t = threadIdx.x;
  __shared__ int cnt;
  if (t == 0) cnt = 0;
  __syncthreads();
  if (t < WIDX_ && idxs[b * WIDX_ + t] > 0) atomicAdd(&cnt, 1);
  __syncthreads();
  if (t == 0) {
    int sb = cnt - 2;
    meta[b * 4 + 0] = sb;
    meta[b * 4 + 1] = idxs[b * WIDX_ + sb];  // sls
    meta[b * 4 + 2] = blen[b] - 1;           // last
  }
}

// ---------------- gather sent_emb (y<S) and arg_emb (y>=S) ----------------
__global__ void k_gather(const float* __restrict__ emb, const int* __restrict__ idxs,
                         const int* __restrict__ meta, float* __restrict__ sent_emb,
                         float* __restrict__ arg_emb) {
  int b = blockIdx.y, y = blockIdx.x, t = threadIdx.x;
  int sb = meta[b * 4 + 0], sls = meta[b * 4 + 1], last = meta[b * 4 + 2];
  if (y < S_) {
    int s = y;
    float* dst = sent_emb + ((size_t)b * S_ + s) * D_;
    if (s < sb) {
      const float* src = emb + ((size_t)b * L_ + idxs[b * WIDX_ + s]) * D_;
      for (int d = t; d < D_; d += 256) dst[d] = src[d];
    } else {
      for (int d = t; d < D_; d += 256) dst[d] = 0.f;
    }
  } else {
    int l = y - S_;
    int pos = sls + 1 + l;
    float* dst = arg_emb + ((size_t)b * LA_ + l) * D_;
    if (pos < last) {
      int p = pos > (L_ - 1) ? (L_ - 1) : pos;
      const float* src = emb + ((size_t)b * L_ + p) * D_;
      for (int d = t; d < D_; d += 256) dst[d] = src[d];
    } else {
      for (int d = t; d < D_; d += 256) dst[d] = 0.f;
    }
  }
}

// ---------------- trig: weighted mean over triggers ----------------
__global__ void k_trig(const float* __restrict__ sent_emb, const float* __restrict__ is_trig,
                       float* __restrict__ trig) {
  int b = blockIdx.y;
  int d = blockIdx.x * 256 + threadIdx.x;
  float acc = 0.f, den = 0.f;
  for (int s = 0; s < S_; s++) {
    float w = is_trig[b * S_ + s];
    den += w;
    if (w != 0.f) acc += w * sent_emb[((size_t)b * S_ + s) * D_ + d];
  }
  trig[b * D_ + d] = acc / den;
}

// ---------------- entity0 = ent_map^T @ sent_emb ; writes split bf16 e0, e0*trig; nonempty --
__global__ __launch_bounds__(256) void k_entity0(const float* __restrict__ sent_emb,
                                                 const float* __restrict__ ent_map,
                                                 const float* __restrict__ trig,
                                                 unsigned short* __restrict__ e0h,
                                                 unsigned short* __restrict__ e0l,
                                                 unsigned short* __restrict__ e0th,
                                                 unsigned short* __restrict__ e0tl,
                                                 float* __restrict__ ne) {
  int b = blockIdx.y, e = blockIdx.x, t = threadIdx.x;
  float a0 = 0.f, a1 = 0.f, a2 = 0.f;
  for (int s = 0; s < S_; s++) {
    float w = ent_map[((size_t)b * S_ + s) * E_ + e];
    if (w != 0.f) {
      const float* r = sent_emb + ((size_t)b * S_ + s) * D_;
      a0 += w * r[t]; a1 += w * r[t + 256]; a2 += w * r[t + 512];
    }
  }
  size_t o = ((size_t)b * E_ + e) * D_;
  const float* tr = trig + b * D_;
  unsigned short h, lo;
  split_bf16(a0, h, lo); e0h[o + t] = h; e0l[o + t] = lo;
  split_bf16(a1, h, lo); e0h[o + t + 256] = h; e0l[o + t + 256] = lo;
  split_bf16(a2, h, lo); e0h[o + t + 512] = h; e0l[o + t + 512] = lo;
  split_bf16(a0 * tr[t], h, lo); e0th[o + t] = h; e0tl[o + t] = lo;
  split_bf16(a1 * tr[t + 256], h, lo); e0th[o + t + 256] = h; e0tl[o + t + 256] = lo;
  split_bf16(a2 * tr[t + 512], h, lo); e0th[o + t + 512] = h; e0tl[o + t + 512] = lo;
  __shared__ float red[256];
  red[t] = fabsf(a0) + fabsf(a1) + fabsf(a2);
  __syncthreads();
  for (int s2 = 128; s2 > 0; s2 >>= 1) {
    if (t < s2) red[t] += red[t + s2];
    __syncthreads();
  }
  if (t == 0) ne[b * E_ + e] = (red[0] > 0.f) ? 1.f : 0.f;
}

// ---------------- generic weighted sum: O[b,x,:] = sum_y W[b, y*sy + x*sx] * V[b,y,:] ------
// Om (fp32) and oh/ol (split bf16) are each optional (nullptr to skip).
__global__ __launch_bounds__(256) void k_wsum(const float* __restrict__ Wm, int wstride, int sy,
                                              int sx, const float* __restrict__ Vm,
                                              float* __restrict__ Om,
                                              unsigned short* __restrict__ oh,
                                              unsigned short* __restrict__ ol, int Y) {
  int b = blockIdx.y, x = blockIdx.x, t = threadIdx.x;
  float a0 = 0.f, a1 = 0.f, a2 = 0.f;
  const float* wb = Wm + (size_t)b * wstride + (size_t)x * sx;
  const float* vb = Vm + (size_t)b * Y * D_;
  for (int y = 0; y < Y; y++) {
    float w = wb[(size_t)y * sy];
    if (w != 0.f) {
      const float* r = vb + (size_t)y * D_;
      a0 += w * r[t]; a1 += w * r[t + 256]; a2 += w * r[t + 512];
    }
  }
  size_t oidx = ((size_t)b * gridDim.x + x) * D_;
  if (Om) {
    Om[oidx + t] = a0; Om[oidx + t + 256] = a1; Om[oidx + t + 512] = a2;
  }
  if (oh) {
    unsigned short h, lo;
    split_bf16(a0, h, lo); oh[oidx + t] = h; ol[oidx + t] = lo;
    split_bf16(a1, h, lo); oh[oidx + t + 256] = h; ol[oidx + t + 256] = lo;
    split_bf16(a2, h, lo); oh[oidx + t + 512] = h; ol[oidx + t + 512] = lo;
  }
}

// ---------------- tb[b,d] = b_ta[d] + sum_k trig[b,k]*W_ta[(D+k)*D + d] ----------------
__global__ void k_tb(const float* __restrict__ trig, const float* __restrict__ W_ta,
                     const float* __restrict__ b_ta, float* __restrict__ tb) {
  int b = blockIdx.y;
  int d = blockIdx.x * 256 + threadIdx.x;
  float acc0 = b_ta[d], acc1 = 0.f, acc2 = 0.f, acc3 = 0.f;
  float acc4 = 0.f, acc5 = 0.f, acc6 = 0.f, acc7 = 0.f;
  const float* tr = trig + b * D_;
  const float* w = W_ta + (size_t)D_ * D_ + d;
  for (int k = 0; k < D_; k += 8) {
    acc0 += tr[k + 0] * w[(size_t)(k + 0) * D_];
    acc1 += tr[k + 1] * w[(size_t)(k + 1) * D_];
    acc2 += tr[k + 2] * w[(size_t)(k + 2) * D_];
    acc3 += tr[k + 3] * w[(size_t)(k + 3) * D_];
    acc4 += tr[k + 4] * w[(size_t)(k + 4) * D_];
    acc5 += tr[k + 5] * w[(size_t)(k + 5) * D_];
    acc6 += tr[k + 6] * w[(size_t)(k + 6) * D_];
    acc7 += tr[k + 7] * w[(size_t)(k + 7) * D_];
  }
  tb[b * D_ + d] = ((acc0 + acc1) + (acc2 + acc3)) + ((acc4 + acc5) + (acc6 + acc7));
}

// ---------------- transpose + bf16-split weights: src[K][N] fp32 -> th/tl[N][K] ----------
__global__ __launch_bounds__(256) void k_cvtT(const float* __restrict__ src, int K, int N,
                                              unsigned short* __restrict__ th,
                                              unsigned short* __restrict__ tl) {
  __shared__ float tile[32][33];
  int k0 = blockIdx.x * 32, n0 = blockIdx.y * 32;
  int tr = threadIdx.x >> 3, c4 = (threadIdx.x & 7) * 4;
  float4 v = *(const float4*)(src + (size_t)(k0 + tr) * N + n0 + c4);
  tile[tr][c4] = v.x; tile[tr][c4 + 1] = v.y; tile[tr][c4 + 2] = v.z; tile[tr][c4 + 3] = v.w;
  __syncthreads();
  unsigned short h[4], l[4];
#pragma unroll
  for (int i = 0; i < 4; ++i) split_bf16(tile[c4 + i][tr], h[i], l[i]);
  size_t oo = (size_t)(n0 + tr) * K + k0 + c4;
  th[oo + 0] = h[0]; th[oo + 1] = h[1]; th[oo + 2] = h[2]; th[oo + 3] = h[3];
  tl[oo + 0] = l[0]; tl[oo + 1] = l[1]; tl[oo + 2] = l[2]; tl[oo + 3] = l[3];
}

// ---------------- MFMA GEMM, split-bf16 3-term (hi*hi + hi*lo + lo*hi) ----------------
// 64x64 tile / block, 4 waves as 2x2 of 32x32, BK=32, v_mfma_f32_16x16x32_bf16.
// A inputs: row-major [M][768] bf16 hi/lo.  B inputs: pre-transposed [N][Ktot] hi/lo.
// grid-z job select like the old k_gemmz; entn epilogue fuses +tb and *ne.
__global__ __launch_bounds__(256) void k_mgemm(
    int phase,
    const unsigned short* __restrict__ e0h, const unsigned short* __restrict__ e0l,
    const unsigned short* __restrict__ e0th, const unsigned short* __restrict__ e0tl,
    const unsigned short* __restrict__ Ah2hh, const unsigned short* __restrict__ Ah2hl,
    const unsigned short* __restrict__ argmh, const unsigned short* __restrict__ argml,
    const unsigned short* __restrict__ Au2uh, const unsigned short* __restrict__ Au2ul,
    const unsigned short* __restrict__ tokAh, const unsigned short* __restrict__ tokAl,
    const unsigned short* __restrict__ argTh, const unsigned short* __restrict__ argTl,
    const unsigned short* __restrict__ WtaTh, const unsigned short* __restrict__ WtaTl,
    const unsigned short* __restrict__ W1Th, const unsigned short* __restrict__ W1Tl,
    float* __restrict__ entn, float* __restrict__ PeA, float* __restrict__ PaA,
    float* __restrict__ PeC, float* __restrict__ PaC,
    const float* __restrict__ tb, const float* __restrict__ ne) {
  int z = blockIdx.z;
  const unsigned short *A0h_, *A0l_, *A1h_, *A1l_, *Bh_, *Bl_;
  float* C;
  size_t koff0, koff1;
  int bstride, mtiles, niter, N, ep = 0;
  if (phase == 0) {
    if (z == 0) {
      A0h_ = e0h; A0l_ = e0l; A1h_ = e0th; A1l_ = e0tl; Bh_ = WtaTh; Bl_ = WtaTl;
      bstride = 2304; koff0 = 0; koff1 = 1536; C = entn; N = 768; mtiles = 16; niter = 48; ep = 1;
    } else if (z == 1) {
      A0h_ = e0h; A0l_ = e0l; A1h_ = Ah2hh; A1l_ = Ah2hl; Bh_ = W1Th; Bl_ = W1Tl;
      bstride = 4608; koff0 = 0; koff1 = 3 * 768; C = PeA; N = 1024; mtiles = 16; niter = 48;
    } else {
      A0h_ = argmh; A0l_ = argml; A1h_ = Au2uh; A1l_ = Au2ul; Bh_ = W1Th; Bl_ = W1Tl;
      bstride = 4608; koff0 = 768; koff1 = 5 * 768; C = PaA; N = 1024; mtiles = 8; niter = 48;
    }
  } else {
    if (z == 0) {
      A0h_ = tokAh; A0l_ = tokAl; A1h_ = tokAh; A1l_ = tokAl; Bh_ = W1Th; Bl_ = W1Tl;
      bstride = 4608; koff0 = 2 * 768; koff1 = 2 * 768; C = PeC; N = 1024; mtiles = 16; niter = 24;
    } else {
      A0h_ = argTh; A0l_ = argTl; A1h_ = argTh; A1l_ = argTl; Bh_ = W1Th; Bl_ = W1Tl;
      bstride = 4608; koff0 = 4 * 768; koff1 = 4 * 768; C = PaC; N = 1024; mtiles = 8; niter = 24;
    }
  }
  int bx = blockIdx.x, by = blockIdx.y;
  if (by >= mtiles || bx * 64 >= N) return;  // uniform early exit, before any barrier

  // LDS: [hi/lo][kgroup g=k/8][row][8] -> lane frag read = single ds_read_b128
  __shared__ unsigned short As[2][4][64][8];
  __shared__ unsigned short Bs[2][4][64][8];

  int tid = threadIdx.x;
  int srow = tid >> 2, sg = tid & 3;
  size_t aoff = (size_t)(by * 64 + srow) * 768 + sg * 8;
  size_t brow = (size_t)(bx * 64 + srow) * bstride + sg * 8;
  size_t boff0 = brow + koff0, boff1 = brow + koff1;

  s16x8 rAh = *(const s16x8*)(A0h_ + aoff);
  s16x8 rAl = *(const s16x8*)(A0l_ + aoff);
  s16x8 rBh = *(const s16x8*)(Bh_ + boff0);
  s16x8 rBl = *(const s16x8*)(Bl_ + boff0);

  int lane = tid & 63, wave = tid >> 6;
  int wm = wave >> 1, wn = wave & 1;
  int fg = lane >> 4, fr = lane & 15;
  int ar0 = wm * 32 + fr;
  int bc0 = wn * 32 + fr;

  f32x4 acc00 = {0.f, 0.f, 0.f, 0.f}, acc01 = {0.f, 0.f, 0.f, 0.f};
  f32x4 acc10 = {0.f, 0.f, 0.f, 0.f}, acc11 = {0.f, 0.f, 0.f, 0.f};

  for (int it = 0; it < niter; ++it) {
    __syncthreads();
    *(s16x8*)&As[0][sg][srow][0] = rAh;
    *(s16x8*)&As[1][sg][srow][0] = rAl;
    *(s16x8*)&Bs[0][sg][srow][0] = rBh;
    *(s16x8*)&Bs[1][sg][srow][0] = rBl;
    __syncthreads();
    if (it + 1 < niter) {
      int l = it + 1;
      int p = (l >= 24) ? 1 : 0;
      size_t ka = (size_t)(l - (p ? 24 : 0)) * 32;
      rAh = *(const s16x8*)((p ? A1h_ : A0h_) + aoff + ka);
      rAl = *(const s16x8*)((p ? A1l_ : A0l_) + aoff + ka);
      size_t bo = (p ? boff1 : boff0) + ka;
      rBh = *(const s16x8*)(Bh_ + bo);
      rBl = *(const s16x8*)(Bl_ + bo);
    }
    s16x8 ah0 = *(const s16x8*)&As[0][fg][ar0][0];
    s16x8 ah1 = *(const s16x8*)&As[0][fg][ar0 + 16][0];
    s16x8 al0 = *(const s16x8*)&As[1][fg][ar0][0];
    s16x8 al1 = *(const s16x8*)&As[1][fg][ar0 + 16][0];
    s16x8 bh0 = *(const s16x8*)&Bs[0][fg][bc0][0];
    s16x8 bh1 = *(const s16x8*)&Bs[0][fg][bc0 + 16][0];
    s16x8 bl0 = *(const s16x8*)&Bs[1][fg][bc0][0];
    s16x8 bl1 = *(const s16x8*)&Bs[1][fg][bc0 + 16][0];
    acc00 = __builtin_amdgcn_mfma_f32_16x16x32_bf16(ah0, bh0, acc00, 0, 0, 0);
    acc00 = __builtin_amdgcn_mfma_f32_16x16x32_bf16(ah0, bl0, acc00, 0, 0, 0);
    acc00 = __builtin_amdgcn_mfma_f32_16x16x32_bf16(al0, bh0, acc00, 0, 0, 0);
    acc01 = __builtin_amdgcn_mfma_f32_16x16x32_bf16(ah0, bh1, acc01, 0, 0, 0);
    acc01 = __builtin_amdgcn_mfma_f32_16x16x32_bf16(ah0, bl1, acc01, 0, 0, 0);
    acc01 = __builtin_amdgcn_mfma_f32_16x16x32_bf16(al0, bh1, acc01, 0, 0, 0);
    acc10 = __builtin_amdgcn_mfma_f32_16x16x32_bf16(ah1, bh0, acc10, 0, 0, 0);
    acc10 = __builtin_amdgcn_mfma_f32_16x16x32_bf16(ah1, bl0, acc10, 0, 0, 0);
    acc10 = __builtin_amdgcn_mfma_f32_16x16x32_bf16(al1, bh0, acc10, 0, 0, 0);
    acc11 = __builtin_amdgcn_mfma_f32_16x16x32_bf16(ah1, bh1, acc11, 0, 0, 0);
    acc11 = __builtin_amdgcn_mfma_f32_16x16x32_bf16(ah1, bl1, acc11, 0, 0, 0);
    acc11 = __builtin_amdgcn_mfma_f32_16x16x32_bf16(al1, bh1, acc11, 0, 0, 0);
  }

  // epilogue: C/D layout col = lane&15, row = 4*(lane>>4) + reg [verified m89]
  f32x4 accs[2][2] = {{acc00, acc01}, {acc10, acc11}};
  int colb = bx * 64 + wn * 32 + fr;
  int rowb = by * 64 + wm * 32 + fg * 4;
#pragma unroll
  for (int i = 0; i < 2; ++i) {
#pragma unroll
    for (int j = 0; j < 2; ++j) {
      int col = colb + j * 16;
#pragma unroll
      for (int r = 0; r < 4; ++r) {
        int row = rowb + i * 16 + r;
        float v = accs[i][j][r];
        if (ep) v = (v + tb[(row >> 6) * D_ + col]) * ne[row];
        C[(size_t)row * N + col] = v;
      }
    }
  }
}

// ---------------- score[b,e,a] = dot(entity_new[b,e], arg[b,a]) / sqrt(D) ----------------
__global__ __launch_bounds__(256) void k_score(const float* __restrict__ entn,
                                               const float* __restrict__ argm,
                                               float* __restrict__ score) {
  int b = blockIdx.y, e = blockIdx.x, t = threadIdx.x;
  __shared__ float ent[D_];
  const float* er = entn + ((size_t)b * E_ + e) * D_;
  for (int d = t; d < D_; d += 256) ent[d] = er[d];
  __syncthreads();
  int wave = t >> 6, lane = t & 63;
  const float scale = 0.03608439182435161f;  // 1/sqrt(768)
  for (int a = wave; a < NA_; a += 4) {
    const float* ar = argm + ((size_t)b * NA_ + a) * D_;
    float p = 0.f;
#pragma unroll
    for (int i = 0; i < 12; i++) {
      int d = lane + 64 * i;
      p += ent[d] * ar[d];
    }
    for (int off = 32; off > 0; off >>= 1) p += __shfl_down(p, off);
    if (lane == 0) score[((size_t)b * E_ + e) * NA_ + a] = p * scale;
  }
}

// ---------------- L1 normalize over a (t2a) and over e (a2t) ----------------
__global__ void k_norm(const float* __restrict__ score, float* __restrict__ t2a,
                       float* __restrict__ a2t) {
  int b = blockIdx.x, t = threadIdx.x;
  __shared__ float s[E_ * NA_];
  __shared__ float rs[E_];
  __shared__ float cs[NA_];
  for (int i = t; i < E_ * NA_; i += 256) s[i] = score[(size_t)b * E_ * NA_ + i];
  __syncthreads();
  if (t < E_) {
    float sum = 0.f;
    for (int a = 0; a < NA_; a++) sum += fabsf(s[t * NA_ + a]);
    rs[t] = fmaxf(sum, EPSF);
  } else if (t >= 64 && t < 96) {
    int a = t - 64;
    float sum = 0.f;
    for (int e = 0; e < E_; e++) sum += fabsf(s[e * NA_ + a]);
    cs[a] = fmaxf(sum, EPSF);
  }
  __syncthreads();
  for (int i = t; i < E_ * NA_; i += 256) {
    int e = i >> 5, a = i & 31;
    float v = s[i];
    t2a[(size_t)b * E_ * NA_ + i] = v / rs[e];
    a2t[(size_t)b * E_ * NA_ + i] = v / cs[a];
  }
}

// ---------------- a2a = softmax(arg @ arg^T) ----------------
__global__ __launch_bounds__(256) void k_a2a(const float* __restrict__ argm,
                                             float* __restrict__ a2a) {
  int b = blockIdx.y, a = blockIdx.x, t = threadIdx.x;
  __shared__ float sA[D_];
  __shared__ float lg[NA_];
  const float* ar = argm + ((size_t)b * NA_ + a) * D_;
  for (int d = t; d < D_; d += 256) sA[d] = ar[d];
  __syncthreads();
  int wave = t >> 6, lane = t & 63;
  for (int a2 = wave; a2 < NA_; a2 += 4) {
    const float* br = argm + ((size_t)b * NA_ + a2) * D_;
    float p = 0.f;
#pragma unroll
    for (int i = 0; i < 12; i++) {
      int d = lane + 64 * i;
      p += sA[d] * br[d];
    }
    for (int off = 32; off > 0; off >>= 1) p += __shfl_down(p, off);
    if (lane == 0) lg[a2] = p;
  }
  __syncthreads();
  if (t < 64) {
    float v = (t < NA_) ? lg[t] : -INFINITY;
    float m = v;
    for (int mask = 16; mask > 0; mask >>= 1) m = fmaxf(m, __shfl_xor(m, mask));
    float ex = (t < NA_) ? expf(v - m) : 0.f;
    float sm = ex;
    for (int mask = 16; mask > 0; mask >>= 1) sm += __shfl_xor(sm, mask);
    if (t < NA_) a2a[((size_t)b * NA_ + a) * NA_ + t] = ex / sm;
  }
}

// ---------------- t2t: gathered, head-mean, per-att row-normalized, averaged ----------------
__global__ __launch_bounds__(128) void k_t2t(const float* __restrict__ att0,
                                             const float* __restrict__ att1,
                                             const float* __restrict__ att2,
                                             const int* __restrict__ idxs,
                                             const int* __restrict__ meta,
                                             float* __restrict__ t2t) {
  int b = blockIdx.y, s = blockIdx.x, t = threadIdx.x;
  int sb = meta[b * 4 + 0];
  float* out = t2t + ((size_t)b * S_ + s) * S_;
  if (s >= sb) {
    for (int j = t; j < S_; j += 128) out[j] = 0.f;
    return;
  }
  int Is = idxs[b * WIDX_ + s];
  int It = (t < S_) ? idxs[b * WIDX_ + t] : 0;
  __shared__ float row[256];
  __shared__ float red[128];
  const float* atts[3] = {att0, att1, att2};
  float accout = 0.f;
  for (int q = 0; q < 3; q++) {
    float r0 = 0.f, r1 = 0.f;
    const float* base = atts[q] + (((size_t)b * H_) * L_ + Is) * L_;
    for (int h = 0; h < H_; h++) {
      const float* rp = base + (size_t)h * L_ * L_;
      r0 += rp[t];
      r1 += rp[t + 128];
    }
    row[t] = r0;
    row[t + 128] = r1;
    __syncthreads();
    float v = (t < sb) ? row[It] * (1.f / 12.f) : 0.f;
    red[t] = v;
    __syncthreads();
    for (int s2 = 64; s2 > 0; s2 >>= 1) {
      if (t < s2) red[t] += red[t + s2];
      __syncthreads();
    }
    float rsum = red[0];
    __syncthreads();
    accout += v / fmaxf(rsum, EPSF) * (1.f / 3.f);
  }
  if (t < S_) out[t] = accout;
}

// ---------------- final: out = gelu(PeA+PeC + PaA+PaC + b1) @ W2 + b2 ----------------
__global__ __launch_bounds__(256) void k_final(const float* __restrict__ PeA,
                                               const float* __restrict__ PeC,
                                               const float* __restrict__ PaA,
                                               const float* __restrict__ PaC,
                                               const float* __restrict__ b1,
                                               const float* __restrict__ W2,
                                               const float* __restrict__ b2,
                                               float* __restrict__ out) {
  int b = blockIdx.y, e = blockIdx.x, t = threadIdx.x;
  size_t po = ((size_t)b * E_ + e) * NHID_;
  int n0 = t * 4;
  float4 pA = *(const float4*)(PeA + po + n0);
  float4 pC = *(const float4*)(PeC + po + n0);
  float4 bb = *(const float4*)(b1 + n0);
  float4 pe4 = make_float4(pA.x + pC.x + bb.x, pA.y + pC.y + bb.y, pA.z + pC.z + bb.z,
                           pA.w + pC.w + bb.w);
  float4 w4 = *(const float4*)(W2 + n0);
  float acc[NA_];
  const float ks = 0.70710678118654752f;
#pragma unroll
  for (int a = 0; a < NA_; ++a) {
    size_t ao = ((size_t)b * NA_ + a) * NHID_ + n0;
    float4 qA = *(const float4*)(PaA + ao);
    float4 qC = *(const float4*)(PaC + ao);
    float x0 = pe4.x + qA.x + qC.x;
    float x1 = pe4.y + qA.y + qC.y;
    float x2 = pe4.z + qA.z + qC.z;
    float x3 = pe4.w + qA.w + qC.w;
    float g0 = 0.5f * x0 * (1.f + erff(x0 * ks));
    float g1 = 0.5f * x1 * (1.f + erff(x1 * ks));
    float g2 = 0.5f * x2 * (1.f + erff(x2 * ks));
    float g3 = 0.5f * x3 * (1.f + erff(x3 * ks));
    acc[a] = g0 * w4.x + g1 * w4.y + g2 * w4.z + g3 * w4.w;
  }
#pragma unroll
  for (int a = 0; a < NA_; ++a) {
    float v = acc[a];
    v += __shfl_xor(v, 32);
    v += __shfl_xor(v, 16);
    v += __shfl_xor(v, 8);
    v += __shfl_xor(v, 4);
    v += __shfl_xor(v, 2);
    v += __shfl_xor(v, 1);
    acc[a] = v;
  }
  __shared__ float part[4][NA_ + 1];
  int wave = t >> 6, lane = t & 63;
  if (lane < NA_) part[wave][lane] = acc[lane];
  __syncthreads();
  if (t < NA_) {
    float v = part[0][t] + part[1][t] + part[2][t] + part[3][t];
    out[((size_t)b * E_ + e) * NA_ + t] = v + b2[0];
  }
}

extern "C" void kernel_launch(void* const* d_in, const int* in_sizes, int n_in,
                              void* d_out, int out_size, void* d_ws, size_t ws_size,
                              hipStream_t stream) {
  const float* emb    = (const float*)d_in[0];
  const float* istrig = (const float*)d_in[1];
  const float* argw   = (const float*)d_in[2];
  const float* entmap = (const float*)d_in[3];
  const float* att0   = (const float*)d_in[4];
  const float* att1   = (const float*)d_in[5];
  const float* att2   = (const float*)d_in[6];
  const float* W_ta   = (const float*)d_in[7];
  const float* b_ta   = (const float*)d_in[8];
  const float* W1     = (const float*)d_in[9];
  const float* b1     = (const float*)d_in[10];
  const float* W2     = (const float*)d_in[11];
  const float* b2     = (const float*)d_in[12];
  const int*   idxs   = (const int*)d_in[13];
  const int*   blen   = (const int*)d_in[14];
  float* out = (float*)d_out;

  float* ws = (float*)d_ws;
  size_t o = 0;
  int* meta = (int*)ws; o += 256;
  float* sent_emb = ws + o; o += (size_t)B_ * S_ * D_;   // dead after phase A -> reused as PeC
  float* arg_emb  = ws + o; o += (size_t)B_ * LA_ * D_;  // dead after argm  -> reused as PaC
  float* trig     = ws + o; o += (size_t)B_ * D_;
  float* argm     = ws + o; o += (size_t)B_ * NA_ * D_;
  float* entn     = ws + o; o += (size_t)B_ * E_ * D_;
  float* tb       = ws + o; o += (size_t)B_ * D_;
  float* ne       = ws + o; o += (size_t)B_ * E_;
  float* score    = ws + o; o += (size_t)B_ * E_ * NA_;
  float* t2a      = ws + o; o += (size_t)B_ * E_ * NA_;
  float* a2t      = ws + o; o += (size_t)B_ * E_ * NA_;
  float* t2t      = ws + o; o += (size_t)B_ * S_ * S_;
  float* ah2h     = ws + o; o += (size_t)B_ * S_ * D_;
  float* a2a      = ws + o; o += (size_t)B_ * NA_ * NA_;
  float* PeA      = ws + o; o += (size_t)B_ * E_ * NHID_;
  float* PaA      = ws + o; o += (size_t)B_ * NA_ * NHID_;
  float* PeC = sent_emb;  // 1.05M floats <= 1.23M
  float* PaC = arg_emb;   // 0.52M floats <= 0.59M

  // split-bf16 region (hi/lo pairs), 16B-aligned
  o = (o + 3) & ~(size_t)3;
  unsigned short* us = (unsigned short*)(ws + o);
  size_t uo = 0;
  unsigned short* e0h   = us + uo; uo += (size_t)B_ * E_ * D_;
  unsigned short* e0l   = us + uo; uo += (size_t)B_ * E_ * D_;
  unsigned short* e0th  = us + uo; uo += (size_t)B_ * E_ * D_;
  unsigned short* e0tl  = us + uo; uo += (size_t)B_ * E_ * D_;
  unsigned short* Ah2hh = us + uo; uo += (size_t)B_ * E_ * D_;
  unsigned short* Ah2hl = us + uo; uo += (size_t)B_ * E_ * D_;
  unsigned short* argmh = us + uo; uo += (size_t)B_ * NA_ * D_;
  unsigned short* argml = us + uo; uo += (size_t)B_ * NA_ * D_;
  unsigned short* Au2uh = us + uo; uo += (size_t)B_ * NA_ * D_;
  unsigned short* Au2ul = us + uo; uo += (size_t)B_ * NA_ * D_;
  unsigned short* tokAh = us + uo; uo += (size_t)B_ * E_ * D_;
  unsigned short* tokAl = us + uo; uo += (size_t)B_ * E_ * D_;
  unsigned short* argTh = us + uo; uo += (size_t)B_ * NA_ * D_;
  unsigned short* argTl = us + uo; uo += (size_t)B_ * NA_ * D_;
  unsigned short* WtaTh = us + uo; uo += (size_t)2304 * 768;
  unsigned short* WtaTl = us + uo; uo += (size_t)2304 * 768;
  unsigned short* W1Th  = us + uo; uo += (size_t)4608 * 1024;
  unsigned short* W1Tl  = us + uo; uo += (size_t)4608 * 1024;

  // ---- phase A: gathers + weight transpose/split + everything not needing entity_new ----
  k_meta<<<B_, 128, 0, stream>>>(idxs, blen, meta);
  k_cvtT<<<dim3(2304 / 32, 768 / 32), 256, 0, stream>>>(W_ta, 2304, 768, WtaTh, WtaTl);
  k_cvtT<<<dim3(4608 / 32, 1024 / 32), 256, 0, stream>>>(W1, 4608, 1024, W1Th, W1Tl);
  k_gather<<<dim3(S_ + LA_, B_), 256, 0, stream>>>(emb, idxs, meta, sent_emb, arg_emb);
  k_trig<<<dim3(3, B_), 256, 0, stream>>>(sent_emb, istrig, trig);
  k_entity0<<<dim3(E_, B_), 256, 0, stream>>>(sent_emb, entmap, trig, e0h, e0l, e0th, e0tl, ne);
  k_wsum<<<dim3(NA_, B_), 256, 0, stream>>>(argw, LA_ * NA_, NA_, 1, arg_emb, argm, argmh,
                                            argml, LA_);
  k_tb<<<dim3(3, B_), 256, 0, stream>>>(trig, W_ta, b_ta, tb);
  k_t2t<<<dim3(S_, B_), 128, 0, stream>>>(att0, att1, att2, idxs, meta, t2t);
  k_wsum<<<dim3(S_, B_), 256, 0, stream>>>(t2t, S_ * S_, 1, S_, sent_emb, ah2h, nullptr,
                                           nullptr, S_);
  k_wsum<<<dim3(E_, B_), 256, 0, stream>>>(entmap, S_ * E_, E_, 1, ah2h, nullptr, Ah2hh,
                                           Ah2hl, S_);
  k_a2a<<<dim3(NA_, B_), 256, 0, stream>>>(argm, a2a);
  k_wsum<<<dim3(NA_, B_), 256, 0, stream>>>(a2a, NA_ * NA_, 1, NA_, argm, nullptr, Au2uh,
                                            Au2ul, NA_);

  // ---- phase B: entn (fused epilogue), PeA, PaA — MFMA split-bf16 ----
  k_mgemm<<<dim3(16, 16, 3), 256, 0, stream>>>(0, e0h, e0l, e0th, e0tl, Ah2hh, Ah2hl, argmh,
                                               argml, Au2uh, Au2ul, tokAh, tokAl, argTh,
                                               argTl, WtaTh, WtaTl, W1Th, W1Tl, entn, PeA,
                                               PaA, PeC, PaC, tb, ne);

  // ---- phase C: score path ----
  k_score<<<dim3(E_, B_), 256, 0, stream>>>(entn, argm, score);
  k_norm<<<B_, 256, 0, stream>>>(score, t2a, a2t);
  k_wsum<<<dim3(E_, B_), 256, 0, stream>>>(t2a, E_ * NA_, 1, NA_, argm, nullptr, tokAh,
                                           tokAl, NA_);
  k_wsum<<<dim3(NA_, B_), 256, 0, stream>>>(a2t, E_ * NA_, NA_, 1, entn, nullptr, argTh,
                                            argTl, E_);

  // ---- phase D: PeC (tokA), PaC (argTok) — MFMA split-bf16 ----
  k_mgemm<<<dim3(16, 16, 2), 256, 0, stream>>>(1, e0h, e0l, e0th, e0tl, Ah2hh, Ah2hl, argmh,
                                               argml, Au2uh, Au2ul, tokAh, tokAl, argTh,
                                               argTl, WtaTh, WtaTl, W1Th, W1Tl, entn, PeA,
                                               PaA, PeC, PaC, tb, ne);

  // ---- final ----
  k_final<<<dim3(E_, B_), 256, 0, stream>>>(PeA, PeC, PaA, PaC, b1, W2, b2, out);
}

// Round 2
// 551.634 us; speedup vs baseline: 1.3808x; 1.1387x over previous
//
#include <hip/hip_runtime.h>
#include <math.h>

#define B_ 16
#define L_ 256
#define S_ 100
#define LA_ 48
#define NA_ 32
#define E_ 64
#define D_ 768
#define H_ 12
#define NHID_ 1024
#define WIDX_ 102
#define EPSF 1e-12f

typedef __attribute__((ext_vector_type(8))) short s16x8;     // 8 bf16 (4 VGPRs) - MFMA A/B frag
typedef __attribute__((ext_vector_type(4))) float f32x4;     // MFMA C/D frag

// split x into bf16 hi + bf16 lo (RTNE), x ~= hi + lo to ~2^-17 rel
__device__ __forceinline__ void split_bf16(float x, unsigned short& h, unsigned short& l) {
  unsigned u = __float_as_uint(x);
  unsigned hr = u + 0x7FFFu + ((u >> 16) & 1u);
  h = (unsigned short)(hr >> 16);
  float r = x - __uint_as_float(hr & 0xFFFF0000u);
  unsigned u2 = __float_as_uint(r);
  unsigned lr = u2 + 0x7FFFu + ((u2 >> 16) & 1u);
  l = (unsigned short)(lr >> 16);
}

// ---------------- meta: per-b sb, sls, last ----------------
__global__ void k_meta(const int* __restrict__ idxs, const int* __restrict__ blen,
                       int* __restrict__ meta) {
  int b = blockIdx.x, t = threadIdx.x;
  __shared__ int cnt;
  if (t == 0) cnt = 0;
  __syncthreads();
  if (t < WIDX_ && idxs[b * WIDX_ + t] > 0) atomicAdd(&cnt, 1);
  __syncthreads();
  if (t == 0) {
    int sb = cnt - 2;
    meta[b * 4 + 0] = sb;
    meta[b * 4 + 1] = idxs[b * WIDX_ + sb];  // sls
    meta[b * 4 + 2] = blen[b] - 1;           // last
  }
}

// ---------------- gather sent_emb (y<S) and arg_emb (y>=S) ----------------
__global__ void k_gather(const float* __restrict__ emb, const int* __restrict__ idxs,
                         const int* __restrict__ meta, float* __restrict__ sent_emb,
                         float* __restrict__ arg_emb) {
  int b = blockIdx.y, y = blockIdx.x, t = threadIdx.x;
  int sb = meta[b * 4 + 0], sls = meta[b * 4 + 1], last = meta[b * 4 + 2];
  if (y < S_) {
    int s = y;
    float* dst = sent_emb + ((size_t)b * S_ + s) * D_;
    if (s < sb) {
      const float* src = emb + ((size_t)b * L_ + idxs[b * WIDX_ + s]) * D_;
      for (int d = t; d < D_; d += 256) dst[d] = src[d];
    } else {
      for (int d = t; d < D_; d += 256) dst[d] = 0.f;
    }
  } else {
    int l = y - S_;
    int pos = sls + 1 + l;
    float* dst = arg_emb + ((size_t)b * LA_ + l) * D_;
    if (pos < last) {
      int p = pos > (L_ - 1) ? (L_ - 1) : pos;
      const float* src = emb + ((size_t)b * L_ + p) * D_;
      for (int d = t; d < D_; d += 256) dst[d] = src[d];
    } else {
      for (int d = t; d < D_; d += 256) dst[d] = 0.f;
    }
  }
}

// ---------------- trig: weighted mean over triggers ----------------
__global__ void k_trig(const float* __restrict__ sent_emb, const float* __restrict__ is_trig,
                       float* __restrict__ trig) {
  int b = blockIdx.y;
  int d = blockIdx.x * 256 + threadIdx.x;
  float acc = 0.f, den = 0.f;
  for (int s = 0; s < S_; s++) {
    float w = is_trig[b * S_ + s];
    den += w;
    if (w != 0.f) acc += w * sent_emb[((size_t)b * S_ + s) * D_ + d];
  }
  trig[b * D_ + d] = acc / den;
}

// ---------------- entity0 = ent_map^T @ sent_emb ; writes split bf16 e0, e0*trig; nonempty --
__global__ __launch_bounds__(256) void k_entity0(const float* __restrict__ sent_emb,
                                                 const float* __restrict__ ent_map,
                                                 const float* __restrict__ trig,
                                                 unsigned short* __restrict__ e0h,
                                                 unsigned short* __restrict__ e0l,
                                                 unsigned short* __restrict__ e0th,
                                                 unsigned short* __restrict__ e0tl,
                                                 float* __restrict__ ne) {
  int b = blockIdx.y, e = blockIdx.x, t = threadIdx.x;
  float a0 = 0.f, a1 = 0.f, a2 = 0.f;
  for (int s = 0; s < S_; s++) {
    float w = ent_map[((size_t)b * S_ + s) * E_ + e];
    if (w != 0.f) {
      const float* r = sent_emb + ((size_t)b * S_ + s) * D_;
      a0 += w * r[t]; a1 += w * r[t + 256]; a2 += w * r[t + 512];
    }
  }
  size_t o = ((size_t)b * E_ + e) * D_;
  const float* tr = trig + b * D_;
  unsigned short h, lo;
  split_bf16(a0, h, lo); e0h[o + t] = h; e0l[o + t] = lo;
  split_bf16(a1, h, lo); e0h[o + t + 256] = h; e0l[o + t + 256] = lo;
  split_bf16(a2, h, lo); e0h[o + t + 512] = h; e0l[o + t + 512] = lo;
  split_bf16(a0 * tr[t], h, lo); e0th[o + t] = h; e0tl[o + t] = lo;
  split_bf16(a1 * tr[t + 256], h, lo); e0th[o + t + 256] = h; e0tl[o + t + 256] = lo;
  split_bf16(a2 * tr[t + 512], h, lo); e0th[o + t + 512] = h; e0tl[o + t + 512] = lo;
  __shared__ float red[256];
  red[t] = fabsf(a0) + fabsf(a1) + fabsf(a2);
  __syncthreads();
  for (int s2 = 128; s2 > 0; s2 >>= 1) {
    if (t < s2) red[t] += red[t + s2];
    __syncthreads();
  }
  if (t == 0) ne[b * E_ + e] = (red[0] > 0.f) ? 1.f : 0.f;
}

// ---------------- generic weighted sum: O[b,x,:] = sum_y W[b, y*sy + x*sx] * V[b,y,:] ------
// Om (fp32) and oh/ol (split bf16) are each optional (nullptr to skip).
__global__ __launch_bounds__(256) void k_wsum(const float* __restrict__ Wm, int wstride, int sy,
                                              int sx, const float* __restrict__ Vm,
                                              float* __restrict__ Om,
                                              unsigned short* __restrict__ oh,
                                              unsigned short* __restrict__ ol, int Y) {
  int b = blockIdx.y, x = blockIdx.x, t = threadIdx.x;
  float a0 = 0.f, a1 = 0.f, a2 = 0.f;
  const float* wb = Wm + (size_t)b * wstride + (size_t)x * sx;
  const float* vb = Vm + (size_t)b * Y * D_;
  for (int y = 0; y < Y; y++) {
    float w = wb[(size_t)y * sy];
    if (w != 0.f) {
      const float* r = vb + (size_t)y * D_;
      a0 += w * r[t]; a1 += w * r[t + 256]; a2 += w * r[t + 512];
    }
  }
  size_t oidx = ((size_t)b * gridDim.x + x) * D_;
  if (Om) {
    Om[oidx + t] = a0; Om[oidx + t + 256] = a1; Om[oidx + t + 512] = a2;
  }
  if (oh) {
    unsigned short h, lo;
    split_bf16(a0, h, lo); oh[oidx + t] = h; ol[oidx + t] = lo;
    split_bf16(a1, h, lo); oh[oidx + t + 256] = h; ol[oidx + t + 256] = lo;
    split_bf16(a2, h, lo); oh[oidx + t + 512] = h; ol[oidx + t + 512] = lo;
  }
}

// ---------------- tb[b,d] = b_ta[d] + sum_k trig[b,k]*W_ta[(D+k)*D + d] ----------------
__global__ void k_tb(const float* __restrict__ trig, const float* __restrict__ W_ta,
                     const float* __restrict__ b_ta, float* __restrict__ tb) {
  int b = blockIdx.y;
  int d = blockIdx.x * 256 + threadIdx.x;
  float acc0 = b_ta[d], acc1 = 0.f, acc2 = 0.f, acc3 = 0.f;
  float acc4 = 0.f, acc5 = 0.f, acc6 = 0.f, acc7 = 0.f;
  const float* tr = trig + b * D_;
  const float* w = W_ta + (size_t)D_ * D_ + d;
  for (int k = 0; k < D_; k += 8) {
    acc0 += tr[k + 0] * w[(size_t)(k + 0) * D_];
    acc1 += tr[k + 1] * w[(size_t)(k + 1) * D_];
    acc2 += tr[k + 2] * w[(size_t)(k + 2) * D_];
    acc3 += tr[k + 3] * w[(size_t)(k + 3) * D_];
    acc4 += tr[k + 4] * w[(size_t)(k + 4) * D_];
    acc5 += tr[k + 5] * w[(size_t)(k + 5) * D_];
    acc6 += tr[k + 6] * w[(size_t)(k + 6) * D_];
    acc7 += tr[k + 7] * w[(size_t)(k + 7) * D_];
  }
  tb[b * D_ + d] = ((acc0 + acc1) + (acc2 + acc3)) + ((acc4 + acc5) + (acc6 + acc7));
}

// ---------------- transpose + bf16-split weights: src[K][N] fp32 -> th/tl[N][K] ----------
__global__ __launch_bounds__(256) void k_cvtT(const float* __restrict__ src, int K, int N,
                                              unsigned short* __restrict__ th,
                                              unsigned short* __restrict__ tl) {
  __shared__ float tile[32][33];
  int k0 = blockIdx.x * 32, n0 = blockIdx.y * 32;
  int tr = threadIdx.x >> 3, c4 = (threadIdx.x & 7) * 4;
  float4 v = *(const float4*)(src + (size_t)(k0 + tr) * N + n0 + c4);
  tile[tr][c4] = v.x; tile[tr][c4 + 1] = v.y; tile[tr][c4 + 2] = v.z; tile[tr][c4 + 3] = v.w;
  __syncthreads();
  unsigned short h[4], l[4];
#pragma unroll
  for (int i = 0; i < 4; ++i) split_bf16(tile[c4 + i][tr], h[i], l[i]);
  size_t oo = (size_t)(n0 + tr) * K + k0 + c4;
  th[oo + 0] = h[0]; th[oo + 1] = h[1]; th[oo + 2] = h[2]; th[oo + 3] = h[3];
  tl[oo + 0] = l[0]; tl[oo + 1] = l[1]; tl[oo + 2] = l[2]; tl[oo + 3] = l[3];
}

// ---------------- MFMA GEMM, split-bf16 3-term (hi*hi + hi*lo + lo*hi) ----------------
// 64x64 tile / block, 4 waves as 2x2 of 32x32, BK=32, v_mfma_f32_16x16x32_bf16.
// A inputs: row-major [M][768] bf16 hi/lo.  B inputs: pre-transposed [N][Ktot] hi/lo.
// grid-z job select; epilogues: ep=1 entn(+tb,*ne), ep=2 (+PeA+b1), ep=3 (+PaA).
__global__ __launch_bounds__(256) void k_mgemm(
    int phase,
    const unsigned short* __restrict__ e0h, const unsigned short* __restrict__ e0l,
    const unsigned short* __restrict__ e0th, const unsigned short* __restrict__ e0tl,
    const unsigned short* __restrict__ Ah2hh, const unsigned short* __restrict__ Ah2hl,
    const unsigned short* __restrict__ argmh, const unsigned short* __restrict__ argml,
    const unsigned short* __restrict__ Au2uh, const unsigned short* __restrict__ Au2ul,
    const unsigned short* __restrict__ tokAh, const unsigned short* __restrict__ tokAl,
    const unsigned short* __restrict__ argTh, const unsigned short* __restrict__ argTl,
    const unsigned short* __restrict__ WtaTh, const unsigned short* __restrict__ WtaTl,
    const unsigned short* __restrict__ W1Th, const unsigned short* __restrict__ W1Tl,
    float* __restrict__ entn, float* __restrict__ PeA, float* __restrict__ PaA,
    float* __restrict__ PeC, float* __restrict__ PaC,
    const float* __restrict__ tb, const float* __restrict__ ne,
    const float* __restrict__ b1) {
  int z = blockIdx.z;
  const unsigned short *A0h_, *A0l_, *A1h_, *A1l_, *Bh_, *Bl_;
  float* C;
  size_t koff0, koff1;
  int bstride, mtiles, niter, N, ep = 0;
  if (phase == 0) {
    if (z == 0) {
      A0h_ = e0h; A0l_ = e0l; A1h_ = e0th; A1l_ = e0tl; Bh_ = WtaTh; Bl_ = WtaTl;
      bstride = 2304; koff0 = 0; koff1 = 1536; C = entn; N = 768; mtiles = 16; niter = 48; ep = 1;
    } else if (z == 1) {
      A0h_ = e0h; A0l_ = e0l; A1h_ = Ah2hh; A1l_ = Ah2hl; Bh_ = W1Th; Bl_ = W1Tl;
      bstride = 4608; koff0 = 0; koff1 = 3 * 768; C = PeA; N = 1024; mtiles = 16; niter = 48;
    } else {
      A0h_ = argmh; A0l_ = argml; A1h_ = Au2uh; A1l_ = Au2ul; Bh_ = W1Th; Bl_ = W1Tl;
      bstride = 4608; koff0 = 768; koff1 = 5 * 768; C = PaA; N = 1024; mtiles = 8; niter = 48;
    }
  } else {
    if (z == 0) {
      A0h_ = tokAh; A0l_ = tokAl; A1h_ = tokAh; A1l_ = tokAl; Bh_ = W1Th; Bl_ = W1Tl;
      bstride = 4608; koff0 = 2 * 768; koff1 = 2 * 768; C = PeC; N = 1024; mtiles = 16;
      niter = 24; ep = 2;
    } else {
      A0h_ = argTh; A0l_ = argTl; A1h_ = argTh; A1l_ = argTl; Bh_ = W1Th; Bl_ = W1Tl;
      bstride = 4608; koff0 = 4 * 768; koff1 = 4 * 768; C = PaC; N = 1024; mtiles = 8;
      niter = 24; ep = 3;
    }
  }
  int bx = blockIdx.x, by = blockIdx.y;
  if (by >= mtiles || bx * 64 >= N) return;  // uniform early exit, before any barrier

  // LDS: [hi/lo][kgroup g=k/8][row][8] -> lane frag read = single ds_read_b128
  __shared__ unsigned short As[2][4][64][8];
  __shared__ unsigned short Bs[2][4][64][8];

  int tid = threadIdx.x;
  int srow = tid >> 2, sg = tid & 3;
  size_t aoff = (size_t)(by * 64 + srow) * 768 + sg * 8;
  size_t brow = (size_t)(bx * 64 + srow) * bstride + sg * 8;
  size_t boff0 = brow + koff0, boff1 = brow + koff1;

  s16x8 rAh = *(const s16x8*)(A0h_ + aoff);
  s16x8 rAl = *(const s16x8*)(A0l_ + aoff);
  s16x8 rBh = *(const s16x8*)(Bh_ + boff0);
  s16x8 rBl = *(const s16x8*)(Bl_ + boff0);

  int lane = tid & 63, wave = tid >> 6;
  int wm = wave >> 1, wn = wave & 1;
  int fg = lane >> 4, fr = lane & 15;
  int ar0 = wm * 32 + fr;
  int bc0 = wn * 32 + fr;

  f32x4 acc00 = {0.f, 0.f, 0.f, 0.f}, acc01 = {0.f, 0.f, 0.f, 0.f};
  f32x4 acc10 = {0.f, 0.f, 0.f, 0.f}, acc11 = {0.f, 0.f, 0.f, 0.f};

  for (int it = 0; it < niter; ++it) {
    __syncthreads();
    *(s16x8*)&As[0][sg][srow][0] = rAh;
    *(s16x8*)&As[1][sg][srow][0] = rAl;
    *(s16x8*)&Bs[0][sg][srow][0] = rBh;
    *(s16x8*)&Bs[1][sg][srow][0] = rBl;
    __syncthreads();
    if (it + 1 < niter) {
      int l = it + 1;
      int p = (l >= 24) ? 1 : 0;
      size_t ka = (size_t)(l - (p ? 24 : 0)) * 32;
      rAh = *(const s16x8*)((p ? A1h_ : A0h_) + aoff + ka);
      rAl = *(const s16x8*)((p ? A1l_ : A0l_) + aoff + ka);
      size_t bo = (p ? boff1 : boff0) + ka;
      rBh = *(const s16x8*)(Bh_ + bo);
      rBl = *(const s16x8*)(Bl_ + bo);
    }
    s16x8 ah0 = *(const s16x8*)&As[0][fg][ar0][0];
    s16x8 ah1 = *(const s16x8*)&As[0][fg][ar0 + 16][0];
    s16x8 al0 = *(const s16x8*)&As[1][fg][ar0][0];
    s16x8 al1 = *(const s16x8*)&As[1][fg][ar0 + 16][0];
    s16x8 bh0 = *(const s16x8*)&Bs[0][fg][bc0][0];
    s16x8 bh1 = *(const s16x8*)&Bs[0][fg][bc0 + 16][0];
    s16x8 bl0 = *(const s16x8*)&Bs[1][fg][bc0][0];
    s16x8 bl1 = *(const s16x8*)&Bs[1][fg][bc0 + 16][0];
    acc00 = __builtin_amdgcn_mfma_f32_16x16x32_bf16(ah0, bh0, acc00, 0, 0, 0);
    acc00 = __builtin_amdgcn_mfma_f32_16x16x32_bf16(ah0, bl0, acc00, 0, 0, 0);
    acc00 = __builtin_amdgcn_mfma_f32_16x16x32_bf16(al0, bh0, acc00, 0, 0, 0);
    acc01 = __builtin_amdgcn_mfma_f32_16x16x32_bf16(ah0, bh1, acc01, 0, 0, 0);
    acc01 = __builtin_amdgcn_mfma_f32_16x16x32_bf16(ah0, bl1, acc01, 0, 0, 0);
    acc01 = __builtin_amdgcn_mfma_f32_16x16x32_bf16(al0, bh1, acc01, 0, 0, 0);
    acc10 = __builtin_amdgcn_mfma_f32_16x16x32_bf16(ah1, bh0, acc10, 0, 0, 0);
    acc10 = __builtin_amdgcn_mfma_f32_16x16x32_bf16(ah1, bl0, acc10, 0, 0, 0);
    acc10 = __builtin_amdgcn_mfma_f32_16x16x32_bf16(al1, bh0, acc10, 0, 0, 0);
    acc11 = __builtin_amdgcn_mfma_f32_16x16x32_bf16(ah1, bh1, acc11, 0, 0, 0);
    acc11 = __builtin_amdgcn_mfma_f32_16x16x32_bf16(ah1, bl1, acc11, 0, 0, 0);
    acc11 = __builtin_amdgcn_mfma_f32_16x16x32_bf16(al1, bh1, acc11, 0, 0, 0);
  }

  // epilogue: C/D layout col = lane&15, row = 4*(lane>>4) + reg [verified m89]
  f32x4 accs[2][2] = {{acc00, acc01}, {acc10, acc11}};
  int colb = bx * 64 + wn * 32 + fr;
  int rowb = by * 64 + wm * 32 + fg * 4;
#pragma unroll
  for (int i = 0; i < 2; ++i) {
#pragma unroll
    for (int j = 0; j < 2; ++j) {
      int col = colb + j * 16;
#pragma unroll
      for (int r = 0; r < 4; ++r) {
        int row = rowb + i * 16 + r;
        float v = accs[i][j][r];
        if (ep == 1) v = (v + tb[(row >> 6) * D_ + col]) * ne[row];
        else if (ep == 2) v = v + PeA[(size_t)row * NHID_ + col] + b1[col];
        else if (ep == 3) v = v + PaA[(size_t)row * NHID_ + col];
        C[(size_t)row * N + col] = v;
      }
    }
  }
}

// ---------------- score[b,e,a] = dot(entity_new[b,e], arg[b,a]) / sqrt(D) ----------------
__global__ __launch_bounds__(256) void k_score(const float* __restrict__ entn,
                                               const float* __restrict__ argm,
                                               float* __restrict__ score) {
  int b = blockIdx.y, e = blockIdx.x, t = threadIdx.x;
  __shared__ float ent[D_];
  const float* er = entn + ((size_t)b * E_ + e) * D_;
  for (int d = t; d < D_; d += 256) ent[d] = er[d];
  __syncthreads();
  int wave = t >> 6, lane = t & 63;
  const float scale = 0.03608439182435161f;  // 1/sqrt(768)
  for (int a = wave; a < NA_; a += 4) {
    const float* ar = argm + ((size_t)b * NA_ + a) * D_;
    float p = 0.f;
#pragma unroll
    for (int i = 0; i < 12; i++) {
      int d = lane + 64 * i;
      p += ent[d] * ar[d];
    }
    for (int off = 32; off > 0; off >>= 1) p += __shfl_down(p, off);
    if (lane == 0) score[((size_t)b * E_ + e) * NA_ + a] = p * scale;
  }
}

// ---------------- L1 normalize over a (t2a) and over e (a2t) ----------------
__global__ void k_norm(const float* __restrict__ score, float* __restrict__ t2a,
                       float* __restrict__ a2t) {
  int b = blockIdx.x, t = threadIdx.x;
  __shared__ float s[E_ * NA_];
  __shared__ float rs[E_];
  __shared__ float cs[NA_];
  for (int i = t; i < E_ * NA_; i += 256) s[i] = score[(size_t)b * E_ * NA_ + i];
  __syncthreads();
  if (t < E_) {
    float sum = 0.f;
    for (int a = 0; a < NA_; a++) sum += fabsf(s[t * NA_ + a]);
    rs[t] = fmaxf(sum, EPSF);
  } else if (t >= 64 && t < 96) {
    int a = t - 64;
    float sum = 0.f;
    for (int e = 0; e < E_; e++) sum += fabsf(s[e * NA_ + a]);
    cs[a] = fmaxf(sum, EPSF);
  }
  __syncthreads();
  for (int i = t; i < E_ * NA_; i += 256) {
    int e = i >> 5, a = i & 31;
    float v = s[i];
    t2a[(size_t)b * E_ * NA_ + i] = v / rs[e];
    a2t[(size_t)b * E_ * NA_ + i] = v / cs[a];
  }
}

// ---------------- a2a = softmax(arg @ arg^T) ----------------
__global__ __launch_bounds__(256) void k_a2a(const float* __restrict__ argm,
                                             float* __restrict__ a2a) {
  int b = blockIdx.y, a = blockIdx.x, t = threadIdx.x;
  __shared__ float sA[D_];
  __shared__ float lg[NA_];
  const float* ar = argm + ((size_t)b * NA_ + a) * D_;
  for (int d = t; d < D_; d += 256) sA[d] = ar[d];
  __syncthreads();
  int wave = t >> 6, lane = t & 63;
  for (int a2 = wave; a2 < NA_; a2 += 4) {
    const float* br = argm + ((size_t)b * NA_ + a2) * D_;
    float p = 0.f;
#pragma unroll
    for (int i = 0; i < 12; i++) {
      int d = lane + 64 * i;
      p += sA[d] * br[d];
    }
    for (int off = 32; off > 0; off >>= 1) p += __shfl_down(p, off);
    if (lane == 0) lg[a2] = p;
  }
  __syncthreads();
  if (t < 64) {
    float v = (t < NA_) ? lg[t] : -INFINITY;
    float m = v;
    for (int mask = 16; mask > 0; mask >>= 1) m = fmaxf(m, __shfl_xor(m, mask));
    float ex = (t < NA_) ? expf(v - m) : 0.f;
    float sm = ex;
    for (int mask = 16; mask > 0; mask >>= 1) sm += __shfl_xor(sm, mask);
    if (t < NA_) a2a[((size_t)b * NA_ + a) * NA_ + t] = ex / sm;
  }
}

// ---------------- t2t: gathered, head-mean, per-att row-normalized, averaged ----------------
__global__ __launch_bounds__(128) void k_t2t(const float* __restrict__ att0,
                                             const float* __restrict__ att1,
                                             const float* __restrict__ att2,
                                             const int* __restrict__ idxs,
                                             const int* __restrict__ meta,
                                             float* __restrict__ t2t) {
  int b = blockIdx.y, s = blockIdx.x, t = threadIdx.x;
  int sb = meta[b * 4 + 0];
  float* out = t2t + ((size_t)b * S_ + s) * S_;
  if (s >= sb) {
    for (int j = t; j < S_; j += 128) out[j] = 0.f;
    return;
  }
  int Is = idxs[b * WIDX_ + s];
  int It = (t < S_) ? idxs[b * WIDX_ + t] : 0;
  __shared__ float row[256];
  __shared__ float red[128];
  const float* atts[3] = {att0, att1, att2};
  float accout = 0.f;
  for (int q = 0; q < 3; q++) {
    float r0 = 0.f, r1 = 0.f;
    const float* base = atts[q] + (((size_t)b * H_) * L_ + Is) * L_;
    for (int h = 0; h < H_; h++) {
      const float* rp = base + (size_t)h * L_ * L_;
      r0 += rp[t];
      r1 += rp[t + 128];
    }
    row[t] = r0;
    row[t + 128] = r1;
    __syncthreads();
    float v = (t < sb) ? row[It] * (1.f / 12.f) : 0.f;
    red[t] = v;
    __syncthreads();
    for (int s2 = 64; s2 > 0; s2 >>= 1) {
      if (t < s2) red[t] += red[t + s2];
      __syncthreads();
    }
    float rsum = red[0];
    __syncthreads();
    accout += v / fmaxf(rsum, EPSF) * (1.f / 3.f);
  }
  if (t < S_) out[t] = accout;
}

// ---------------- final: out[b,e,a] = sum_n gelu(ps[e,n]+qs[a,n]) * W2[n] + b2 ------------
// ps = PeA+PeC+b1 (fused in phase-D epilogue), qs = PaA+PaC (fused).
// Wave owns a-strided set; lanes own n = lane*4 + i*256 (coalesced float4).
// One 6-op butterfly per output (48 shfl/thread vs 192 in old version).
__global__ __launch_bounds__(256) void k_final(const float* __restrict__ ps,
                                               const float* __restrict__ qs,
                                               const float* __restrict__ W2,
                                               const float* __restrict__ b2,
                                               float* __restrict__ out) {
  int b = blockIdx.y, e = blockIdx.x, t = threadIdx.x;
  int wave = t >> 6, lane = t & 63;
  const float ks = 0.70710678118654752f;
  size_t po = ((size_t)b * E_ + e) * NHID_ + lane * 4;
  float4 p0 = *(const float4*)(ps + po);
  float4 p1 = *(const float4*)(ps + po + 256);
  float4 p2 = *(const float4*)(ps + po + 512);
  float4 p3 = *(const float4*)(ps + po + 768);
  const float* w2p = W2 + lane * 4;
  float4 w0 = *(const float4*)(w2p);
  float4 w1 = *(const float4*)(w2p + 256);
  float4 w2 = *(const float4*)(w2p + 512);
  float4 w3 = *(const float4*)(w2p + 768);
  __shared__ float outs[NA_];
#pragma unroll 2
  for (int a = wave; a < NA_; a += 4) {
    size_t qo = ((size_t)b * NA_ + a) * NHID_ + lane * 4;
    float4 q0 = *(const float4*)(qs + qo);
    float4 q1 = *(const float4*)(qs + qo + 256);
    float4 q2 = *(const float4*)(qs + qo + 512);
    float4 q3 = *(const float4*)(qs + qo + 768);
    float acc = 0.f;
#define GEL4(pp, qq, ww)                                          \
    {                                                             \
      float x0 = pp.x + qq.x, x1 = pp.y + qq.y;                   \
      float x2 = pp.z + qq.z, x3 = pp.w + qq.w;                   \
      float g0 = 0.5f * x0 * (1.f + erff(x0 * ks));               \
      float g1 = 0.5f * x1 * (1.f + erff(x1 * ks));               \
      float g2 = 0.5f * x2 * (1.f + erff(x2 * ks));               \
      float g3 = 0.5f * x3 * (1.f + erff(x3 * ks));               \
      acc += g0 * ww.x + g1 * ww.y + g2 * ww.z + g3 * ww.w;       \
    }
    GEL4(p0, q0, w0)
    GEL4(p1, q1, w1)
    GEL4(p2, q2, w2)
    GEL4(p3, q3, w3)
#undef GEL4
    acc += __shfl_xor(acc, 32);
    acc += __shfl_xor(acc, 16);
    acc += __shfl_xor(acc, 8);
    acc += __shfl_xor(acc, 4);
    acc += __shfl_xor(acc, 2);
    acc += __shfl_xor(acc, 1);
    if (lane == 0) outs[a] = acc;
  }
  __syncthreads();
  if (t < NA_) out[((size_t)b * E_ + e) * NA_ + t] = outs[t] + b2[0];
}

extern "C" void kernel_launch(void* const* d_in, const int* in_sizes, int n_in,
                              void* d_out, int out_size, void* d_ws, size_t ws_size,
                              hipStream_t stream) {
  const float* emb    = (const float*)d_in[0];
  const float* istrig = (const float*)d_in[1];
  const float* argw   = (const float*)d_in[2];
  const float* entmap = (const float*)d_in[3];
  const float* att0   = (const float*)d_in[4];
  const float* att1   = (const float*)d_in[5];
  const float* att2   = (const float*)d_in[6];
  const float* W_ta   = (const float*)d_in[7];
  const float* b_ta   = (const float*)d_in[8];
  const float* W1     = (const float*)d_in[9];
  const float* b1     = (const float*)d_in[10];
  const float* W2     = (const float*)d_in[11];
  const float* b2     = (const float*)d_in[12];
  const int*   idxs   = (const int*)d_in[13];
  const int*   blen   = (const int*)d_in[14];
  float* out = (float*)d_out;

  float* ws = (float*)d_ws;
  size_t o = 0;
  int* meta = (int*)ws; o += 256;
  float* sent_emb = ws + o; o += (size_t)B_ * S_ * D_;   // dead after phase A -> reused as PeC
  float* arg_emb  = ws + o; o += (size_t)B_ * LA_ * D_;  // dead after argm  -> reused as PaC
  float* trig     = ws + o; o += (size_t)B_ * D_;
  float* argm     = ws + o; o += (size_t)B_ * NA_ * D_;
  float* entn     = ws + o; o += (size_t)B_ * E_ * D_;
  float* tb       = ws + o; o += (size_t)B_ * D_;
  float* ne       = ws + o; o += (size_t)B_ * E_;
  float* score    = ws + o; o += (size_t)B_ * E_ * NA_;
  float* t2a      = ws + o; o += (size_t)B_ * E_ * NA_;
  float* a2t      = ws + o; o += (size_t)B_ * E_ * NA_;
  float* t2t      = ws + o; o += (size_t)B_ * S_ * S_;
  float* ah2h     = ws + o; o += (size_t)B_ * S_ * D_;
  float* a2a      = ws + o; o += (size_t)B_ * NA_ * NA_;
  float* PeA      = ws + o; o += (size_t)B_ * E_ * NHID_;
  float* PaA      = ws + o; o += (size_t)B_ * NA_ * NHID_;
  float* PeC = sent_emb;  // 1.05M floats <= 1.23M   (holds PeA+PeC+b1 after phase D)
  float* PaC = arg_emb;   // 0.52M floats <= 0.59M   (holds PaA+PaC after phase D)

  // split-bf16 region (hi/lo pairs), 16B-aligned
  o = (o + 3) & ~(size_t)3;
  unsigned short* us = (unsigned short*)(ws + o);
  size_t uo = 0;
  unsigned short* e0h   = us + uo; uo += (size_t)B_ * E_ * D_;
  unsigned short* e0l   = us + uo; uo += (size_t)B_ * E_ * D_;
  unsigned short* e0th  = us + uo; uo += (size_t)B_ * E_ * D_;
  unsigned short* e0tl  = us + uo; uo += (size_t)B_ * E_ * D_;
  unsigned short* Ah2hh = us + uo; uo += (size_t)B_ * E_ * D_;
  unsigned short* Ah2hl = us + uo; uo += (size_t)B_ * E_ * D_;
  unsigned short* argmh = us + uo; uo += (size_t)B_ * NA_ * D_;
  unsigned short* argml = us + uo; uo += (size_t)B_ * NA_ * D_;
  unsigned short* Au2uh = us + uo; uo += (size_t)B_ * NA_ * D_;
  unsigned short* Au2ul = us + uo; uo += (size_t)B_ * NA_ * D_;
  unsigned short* tokAh = us + uo; uo += (size_t)B_ * E_ * D_;
  unsigned short* tokAl = us + uo; uo += (size_t)B_ * E_ * D_;
  unsigned short* argTh = us + uo; uo += (size_t)B_ * NA_ * D_;
  unsigned short* argTl = us + uo; uo += (size_t)B_ * NA_ * D_;
  unsigned short* WtaTh = us + uo; uo += (size_t)2304 * 768;
  unsigned short* WtaTl = us + uo; uo += (size_t)2304 * 768;
  unsigned short* W1Th  = us + uo; uo += (size_t)4608 * 1024;
  unsigned short* W1Tl  = us + uo; uo += (size_t)4608 * 1024;

  // ---- phase A: gathers + weight transpose/split + everything not needing entity_new ----
  k_meta<<<B_, 128, 0, stream>>>(idxs, blen, meta);
  k_cvtT<<<dim3(2304 / 32, 768 / 32), 256, 0, stream>>>(W_ta, 2304, 768, WtaTh, WtaTl);
  k_cvtT<<<dim3(4608 / 32, 1024 / 32), 256, 0, stream>>>(W1, 4608, 1024, W1Th, W1Tl);
  k_gather<<<dim3(S_ + LA_, B_), 256, 0, stream>>>(emb, idxs, meta, sent_emb, arg_emb);
  k_trig<<<dim3(3, B_), 256, 0, stream>>>(sent_emb, istrig, trig);
  k_entity0<<<dim3(E_, B_), 256, 0, stream>>>(sent_emb, entmap, trig, e0h, e0l, e0th, e0tl, ne);
  k_wsum<<<dim3(NA_, B_), 256, 0, stream>>>(argw, LA_ * NA_, NA_, 1, arg_emb, argm, argmh,
                                            argml, LA_);
  k_tb<<<dim3(3, B_), 256, 0, stream>>>(trig, W_ta, b_ta, tb);
  k_t2t<<<dim3(S_, B_), 128, 0, stream>>>(att0, att1, att2, idxs, meta, t2t);
  k_wsum<<<dim3(S_, B_), 256, 0, stream>>>(t2t, S_ * S_, 1, S_, sent_emb, ah2h, nullptr,
                                           nullptr, S_);
  k_wsum<<<dim3(E_, B_), 256, 0, stream>>>(entmap, S_ * E_, E_, 1, ah2h, nullptr, Ah2hh,
                                           Ah2hl, S_);
  k_a2a<<<dim3(NA_, B_), 256, 0, stream>>>(argm, a2a);
  k_wsum<<<dim3(NA_, B_), 256, 0, stream>>>(a2a, NA_ * NA_, 1, NA_, argm, nullptr, Au2uh,
                                            Au2ul, NA_);

  // ---- phase B: entn (fused epilogue), PeA, PaA — MFMA split-bf16 ----
  k_mgemm<<<dim3(16, 16, 3), 256, 0, stream>>>(0, e0h, e0l, e0th, e0tl, Ah2hh, Ah2hl, argmh,
                                               argml, Au2uh, Au2ul, tokAh, tokAl, argTh,
                                               argTl, WtaTh, WtaTl, W1Th, W1Tl, entn, PeA,
                                               PaA, PeC, PaC, tb, ne, b1);

  // ---- phase C: score path ----
  k_score<<<dim3(E_, B_), 256, 0, stream>>>(entn, argm, score);
  k_norm<<<B_, 256, 0, stream>>>(score, t2a, a2t);
  k_wsum<<<dim3(E_, B_), 256, 0, stream>>>(t2a, E_ * NA_, 1, NA_, argm, nullptr, tokAh,
                                           tokAl, NA_);
  k_wsum<<<dim3(NA_, B_), 256, 0, stream>>>(a2t, E_ * NA_, NA_, 1, entn, nullptr, argTh,
                                            argTl, E_);

  // ---- phase D: PeC = tokA@W1[2]+PeA+b1, PaC = argTok@W1[4]+PaA — fused sums ----
  k_mgemm<<<dim3(16, 16, 2), 256, 0, stream>>>(1, e0h, e0l, e0th, e0tl, Ah2hh, Ah2hl, argmh,
                                               argml, Au2uh, Au2ul, tokAh, tokAl, argTh,
                                               argTl, WtaTh, WtaTl, W1Th, W1Tl, entn, PeA,
                                               PaA, PeC, PaC, tb, ne, b1);

  // ---- final ----
  k_final<<<dim3(E_, B_), 256, 0, stream>>>(PeC, PaC, W2, b2, out);
}

// Round 3
// 504.932 us; speedup vs baseline: 1.5085x; 1.0925x over previous
//
#include <hip/hip_runtime.h>
#include <math.h>

#define B_ 16
#define L_ 256
#define S_ 100
#define LA_ 48
#define NA_ 32
#define E_ 64
#define D_ 768
#define H_ 12
#define NHID_ 1024
#define WIDX_ 102
#define EPSF 1e-12f

typedef __attribute__((ext_vector_type(8))) short s16x8;     // 8 bf16 (4 VGPRs) - MFMA A/B frag
typedef __attribute__((ext_vector_type(4))) float f32x4;     // MFMA C/D frag

// split x into bf16 hi + bf16 lo (RTNE), x ~= hi + lo to ~2^-17 rel
__device__ __forceinline__ void split_bf16(float x, unsigned short& h, unsigned short& l) {
  unsigned u = __float_as_uint(x);
  unsigned hr = u + 0x7FFFu + ((u >> 16) & 1u);
  h = (unsigned short)(hr >> 16);
  float r = x - __uint_as_float(hr & 0xFFFF0000u);
  unsigned u2 = __float_as_uint(r);
  unsigned lr = u2 + 0x7FFFu + ((u2 >> 16) & 1u);
  l = (unsigned short)(lr >> 16);
}

// ---------------- meta: per-b sb, sls, last ----------------
__global__ void k_meta(const int* __restrict__ idxs, const int* __restrict__ blen,
                       int* __restrict__ meta) {
  int b = blockIdx.x, t = threadIdx.x;
  __shared__ int cnt;
  if (t == 0) cnt = 0;
  __syncthreads();
  if (t < WIDX_ && idxs[b * WIDX_ + t] > 0) atomicAdd(&cnt, 1);
  __syncthreads();
  if (t == 0) {
    int sb = cnt - 2;
    meta[b * 4 + 0] = sb;
    meta[b * 4 + 1] = idxs[b * WIDX_ + sb];  // sls
    meta[b * 4 + 2] = blen[b] - 1;           // last
  }
}

// ---------------- gather sent_emb (y<S) and arg_emb (y>=S) ----------------
__global__ void k_gather(const float* __restrict__ emb, const int* __restrict__ idxs,
                         const int* __restrict__ meta, float* __restrict__ sent_emb,
                         float* __restrict__ arg_emb) {
  int b = blockIdx.y, y = blockIdx.x, t = threadIdx.x;
  int sb = meta[b * 4 + 0], sls = meta[b * 4 + 1], last = meta[b * 4 + 2];
  if (y < S_) {
    int s = y;
    float* dst = sent_emb + ((size_t)b * S_ + s) * D_;
    if (s < sb) {
      const float* src = emb + ((size_t)b * L_ + idxs[b * WIDX_ + s]) * D_;
      for (int d = t; d < D_; d += 256) dst[d] = src[d];
    } else {
      for (int d = t; d < D_; d += 256) dst[d] = 0.f;
    }
  } else {
    int l = y - S_;
    int pos = sls + 1 + l;
    float* dst = arg_emb + ((size_t)b * LA_ + l) * D_;
    if (pos < last) {
      int p = pos > (L_ - 1) ? (L_ - 1) : pos;
      const float* src = emb + ((size_t)b * L_ + p) * D_;
      for (int d = t; d < D_; d += 256) dst[d] = src[d];
    } else {
      for (int d = t; d < D_; d += 256) dst[d] = 0.f;
    }
  }
}

// ---------------- trig: weighted mean over triggers ----------------
__global__ void k_trig(const float* __restrict__ sent_emb, const float* __restrict__ is_trig,
                       float* __restrict__ trig) {
  int b = blockIdx.y;
  int d = blockIdx.x * 256 + threadIdx.x;
  float acc = 0.f, den = 0.f;
  for (int s = 0; s < S_; s++) {
    float w = is_trig[b * S_ + s];
    den += w;
    if (w != 0.f) acc += w * sent_emb[((size_t)b * S_ + s) * D_ + d];
  }
  trig[b * D_ + d] = acc / den;
}

// ---------------- entity0 = ent_map^T @ sent_emb ; writes split bf16 e0, e0*trig; nonempty --
__global__ __launch_bounds__(256) void k_entity0(const float* __restrict__ sent_emb,
                                                 const float* __restrict__ ent_map,
                                                 const float* __restrict__ trig,
                                                 unsigned short* __restrict__ e0h,
                                                 unsigned short* __restrict__ e0l,
                                                 unsigned short* __restrict__ e0th,
                                                 unsigned short* __restrict__ e0tl,
                                                 float* __restrict__ ne) {
  int b = blockIdx.y, e = blockIdx.x, t = threadIdx.x;
  float a0 = 0.f, a1 = 0.f, a2 = 0.f;
  for (int s = 0; s < S_; s++) {
    float w = ent_map[((size_t)b * S_ + s) * E_ + e];
    if (w != 0.f) {
      const float* r = sent_emb + ((size_t)b * S_ + s) * D_;
      a0 += w * r[t]; a1 += w * r[t + 256]; a2 += w * r[t + 512];
    }
  }
  size_t o = ((size_t)b * E_ + e) * D_;
  const float* tr = trig + b * D_;
  unsigned short h, lo;
  split_bf16(a0, h, lo); e0h[o + t] = h; e0l[o + t] = lo;
  split_bf16(a1, h, lo); e0h[o + t + 256] = h; e0l[o + t + 256] = lo;
  split_bf16(a2, h, lo); e0h[o + t + 512] = h; e0l[o + t + 512] = lo;
  split_bf16(a0 * tr[t], h, lo); e0th[o + t] = h; e0tl[o + t] = lo;
  split_bf16(a1 * tr[t + 256], h, lo); e0th[o + t + 256] = h; e0tl[o + t + 256] = lo;
  split_bf16(a2 * tr[t + 512], h, lo); e0th[o + t + 512] = h; e0tl[o + t + 512] = lo;
  __shared__ float red[256];
  red[t] = fabsf(a0) + fabsf(a1) + fabsf(a2);
  __syncthreads();
  for (int s2 = 128; s2 > 0; s2 >>= 1) {
    if (t < s2) red[t] += red[t + s2];
    __syncthreads();
  }
  if (t == 0) ne[b * E_ + e] = (red[0] > 0.f) ? 1.f : 0.f;
}

// ---------------- generic weighted sum: O[b,x,:] = sum_y W[b, y*sy + x*sx] * V[b,y,:] ------
// Om (fp32) and oh/ol (split bf16) are each optional (nullptr to skip).
__global__ __launch_bounds__(256) void k_wsum(const float* __restrict__ Wm, int wstride, int sy,
                                              int sx, const float* __restrict__ Vm,
                                              float* __restrict__ Om,
                                              unsigned short* __restrict__ oh,
                                              unsigned short* __restrict__ ol, int Y) {
  int b = blockIdx.y, x = blockIdx.x, t = threadIdx.x;
  float a0 = 0.f, a1 = 0.f, a2 = 0.f;
  const float* wb = Wm + (size_t)b * wstride + (size_t)x * sx;
  const float* vb = Vm + (size_t)b * Y * D_;
  for (int y = 0; y < Y; y++) {
    float w = wb[(size_t)y * sy];
    if (w != 0.f) {
      const float* r = vb + (size_t)y * D_;
      a0 += w * r[t]; a1 += w * r[t + 256]; a2 += w * r[t + 512];
    }
  }
  size_t oidx = ((size_t)b * gridDim.x + x) * D_;
  if (Om) {
    Om[oidx + t] = a0; Om[oidx + t + 256] = a1; Om[oidx + t + 512] = a2;
  }
  if (oh) {
    unsigned short h, lo;
    split_bf16(a0, h, lo); oh[oidx + t] = h; ol[oidx + t] = lo;
    split_bf16(a1, h, lo); oh[oidx + t + 256] = h; ol[oidx + t + 256] = lo;
    split_bf16(a2, h, lo); oh[oidx + t + 512] = h; ol[oidx + t + 512] = lo;
  }
}

// ---------------- tb[b,d] = b_ta[d] + sum_k trig[b,k]*W_ta[(D+k)*D + d] ----------------
__global__ void k_tb(const float* __restrict__ trig, const float* __restrict__ W_ta,
                     const float* __restrict__ b_ta, float* __restrict__ tb) {
  int b = blockIdx.y;
  int d = blockIdx.x * 256 + threadIdx.x;
  float acc0 = b_ta[d], acc1 = 0.f, acc2 = 0.f, acc3 = 0.f;
  float acc4 = 0.f, acc5 = 0.f, acc6 = 0.f, acc7 = 0.f;
  const float* tr = trig + b * D_;
  const float* w = W_ta + (size_t)D_ * D_ + d;
  for (int k = 0; k < D_; k += 8) {
    acc0 += tr[k + 0] * w[(size_t)(k + 0) * D_];
    acc1 += tr[k + 1] * w[(size_t)(k + 1) * D_];
    acc2 += tr[k + 2] * w[(size_t)(k + 2) * D_];
    acc3 += tr[k + 3] * w[(size_t)(k + 3) * D_];
    acc4 += tr[k + 4] * w[(size_t)(k + 4) * D_];
    acc5 += tr[k + 5] * w[(size_t)(k + 5) * D_];
    acc6 += tr[k + 6] * w[(size_t)(k + 6) * D_];
    acc7 += tr[k + 7] * w[(size_t)(k + 7) * D_];
  }
  tb[b * D_ + d] = ((acc0 + acc1) + (acc2 + acc3)) + ((acc4 + acc5) + (acc6 + acc7));
}

// ---------------- transpose + bf16-split weights: src[K][N] fp32 -> th/tl[N][K] ----------
__global__ __launch_bounds__(256) void k_cvtT(const float* __restrict__ src, int K, int N,
                                              unsigned short* __restrict__ th,
                                              unsigned short* __restrict__ tl) {
  __shared__ float tile[32][33];
  int k0 = blockIdx.x * 32, n0 = blockIdx.y * 32;
  int tr = threadIdx.x >> 3, c4 = (threadIdx.x & 7) * 4;
  float4 v = *(const float4*)(src + (size_t)(k0 + tr) * N + n0 + c4);
  tile[tr][c4] = v.x; tile[tr][c4 + 1] = v.y; tile[tr][c4 + 2] = v.z; tile[tr][c4 + 3] = v.w;
  __syncthreads();
  unsigned short h[4], l[4];
#pragma unroll
  for (int i = 0; i < 4; ++i) split_bf16(tile[c4 + i][tr], h[i], l[i]);
  size_t oo = (size_t)(n0 + tr) * K + k0 + c4;
  th[oo + 0] = h[0]; th[oo + 1] = h[1]; th[oo + 2] = h[2]; th[oo + 3] = h[3];
  tl[oo + 0] = l[0]; tl[oo + 1] = l[1]; tl[oo + 2] = l[2]; tl[oo + 3] = l[3];
}

// ---------------- MFMA GEMM, split-bf16 3-term (hi*hi + hi*lo + lo*hi) ----------------
// 64x64 tile / block, 4 waves as 2x2 of 32x32, BK=32, v_mfma_f32_16x16x32_bf16.
// LDS layout [hl][row][c][8] with c = kgroup ^ ((row>>1)&3): conflict-free (floor)
// for both ds_write_b128 (16-lane phase covers 16 distinct 16B slots) and
// ds_read_b128 (16 rows hit each 4-bank group exactly 2x).
// phase 0: z0 entn(+tb,*ne,+split), z1 PeA, z2 PaA, z3 P2=argm@W1[2]
// phase 1: Q2 = entn@W1[4]
__global__ __launch_bounds__(256) void k_mgemm(
    int phase,
    const unsigned short* __restrict__ e0h, const unsigned short* __restrict__ e0l,
    const unsigned short* __restrict__ e0th, const unsigned short* __restrict__ e0tl,
    const unsigned short* __restrict__ Ah2hh, const unsigned short* __restrict__ Ah2hl,
    const unsigned short* __restrict__ argmh, const unsigned short* __restrict__ argml,
    const unsigned short* __restrict__ Au2uh, const unsigned short* __restrict__ Au2ul,
    const unsigned short* __restrict__ WtaTh, const unsigned short* __restrict__ WtaTl,
    const unsigned short* __restrict__ W1Th, const unsigned short* __restrict__ W1Tl,
    float* __restrict__ entn, unsigned short* __restrict__ entnh,
    unsigned short* __restrict__ entnl,
    float* __restrict__ PeA, float* __restrict__ PaA,
    float* __restrict__ P2, float* __restrict__ Q2,
    const float* __restrict__ tb, const float* __restrict__ ne) {
  int z = blockIdx.z;
  const unsigned short *A0h_, *A0l_, *A1h_, *A1l_, *Bh_, *Bl_;
  float* C;
  int koff0, koff1, bstride, mtiles, niter, N, ep = 0;
  if (phase == 0) {
    if (z == 0) {
      A0h_ = e0h; A0l_ = e0l; A1h_ = e0th; A1l_ = e0tl; Bh_ = WtaTh; Bl_ = WtaTl;
      bstride = 2304; koff0 = 0; koff1 = 1536; C = entn; N = 768; mtiles = 16; niter = 48; ep = 1;
    } else if (z == 1) {
      A0h_ = e0h; A0l_ = e0l; A1h_ = Ah2hh; A1l_ = Ah2hl; Bh_ = W1Th; Bl_ = W1Tl;
      bstride = 4608; koff0 = 0; koff1 = 3 * 768; C = PeA; N = 1024; mtiles = 16; niter = 48;
    } else if (z == 2) {
      A0h_ = argmh; A0l_ = argml; A1h_ = Au2uh; A1l_ = Au2ul; Bh_ = W1Th; Bl_ = W1Tl;
      bstride = 4608; koff0 = 768; koff1 = 5 * 768; C = PaA; N = 1024; mtiles = 8; niter = 48;
    } else {
      A0h_ = argmh; A0l_ = argml; A1h_ = argmh; A1l_ = argml; Bh_ = W1Th; Bl_ = W1Tl;
      bstride = 4608; koff0 = 2 * 768; koff1 = 2 * 768; C = P2; N = 1024; mtiles = 8; niter = 24;
    }
  } else {
    A0h_ = entnh; A0l_ = entnl; A1h_ = entnh; A1l_ = entnl; Bh_ = W1Th; Bl_ = W1Tl;
    bstride = 4608; koff0 = 4 * 768; koff1 = 4 * 768; C = Q2; N = 1024; mtiles = 16; niter = 24;
  }
  int bx = blockIdx.x, by = blockIdx.y;
  if (by >= mtiles || bx * 64 >= N) return;  // uniform early exit, before any barrier

  // swizzled LDS: element (kgroup g, row r) stored at [r][g ^ ((r>>1)&3)]
  __shared__ unsigned short As[2][64][4][8];
  __shared__ unsigned short Bs[2][64][4][8];

  int tid = threadIdx.x;
  int srow = tid >> 2, sg = tid & 3;
  int wc = sg ^ ((srow >> 1) & 3);
  size_t aoff = (size_t)(by * 64 + srow) * 768 + sg * 8;
  size_t brow = (size_t)(bx * 64 + srow) * bstride + sg * 8;
  size_t boff0 = brow + koff0, boff1 = brow + koff1;

  s16x8 rAh = *(const s16x8*)(A0h_ + aoff);
  s16x8 rAl = *(const s16x8*)(A0l_ + aoff);
  s16x8 rBh = *(const s16x8*)(Bh_ + boff0);
  s16x8 rBl = *(const s16x8*)(Bl_ + boff0);

  int lane = tid & 63, wave = tid >> 6;
  int wm = wave >> 1, wn = wave & 1;
  int fg = lane >> 4, fr = lane & 15;
  int ar0 = wm * 32 + fr;
  int bc0 = wn * 32 + fr;
  int ca = fg ^ ((ar0 >> 1) & 3);   // same for ar0+16 (bit4 doesn't affect (r>>1)&3)
  int cb = fg ^ ((bc0 >> 1) & 3);

  f32x4 acc00 = {0.f, 0.f, 0.f, 0.f}, acc01 = {0.f, 0.f, 0.f, 0.f};
  f32x4 acc10 = {0.f, 0.f, 0.f, 0.f}, acc11 = {0.f, 0.f, 0.f, 0.f};

  for (int it = 0; it < niter; ++it) {
    __syncthreads();
    *(s16x8*)&As[0][srow][wc][0] = rAh;
    *(s16x8*)&As[1][srow][wc][0] = rAl;
    *(s16x8*)&Bs[0][srow][wc][0] = rBh;
    *(s16x8*)&Bs[1][srow][wc][0] = rBl;
    __syncthreads();
    if (it + 1 < niter) {
      int l = it + 1;
      int p = (l >= 24) ? 1 : 0;
      size_t ka = (size_t)(l - (p ? 24 : 0)) * 32;
      rAh = *(const s16x8*)((p ? A1h_ : A0h_) + aoff + ka);
      rAl = *(const s16x8*)((p ? A1l_ : A0l_) + aoff + ka);
      size_t bo = (p ? boff1 : boff0) + ka;
      rBh = *(const s16x8*)(Bh_ + bo);
      rBl = *(const s16x8*)(Bl_ + bo);
    }
    s16x8 ah0 = *(const s16x8*)&As[0][ar0][ca][0];
    s16x8 ah1 = *(const s16x8*)&As[0][ar0 + 16][ca][0];
    s16x8 al0 = *(const s16x8*)&As[1][ar0][ca][0];
    s16x8 al1 = *(const s16x8*)&As[1][ar0 + 16][ca][0];
    s16x8 bh0 = *(const s16x8*)&Bs[0][bc0][cb][0];
    s16x8 bh1 = *(const s16x8*)&Bs[0][bc0 + 16][cb][0];
    s16x8 bl0 = *(const s16x8*)&Bs[1][bc0][cb][0];
    s16x8 bl1 = *(const s16x8*)&Bs[1][bc0 + 16][cb][0];
    acc00 = __builtin_amdgcn_mfma_f32_16x16x32_bf16(ah0, bh0, acc00, 0, 0, 0);
    acc00 = __builtin_amdgcn_mfma_f32_16x16x32_bf16(ah0, bl0, acc00, 0, 0, 0);
    acc00 = __builtin_amdgcn_mfma_f32_16x16x32_bf16(al0, bh0, acc00, 0, 0, 0);
    acc01 = __builtin_amdgcn_mfma_f32_16x16x32_bf16(ah0, bh1, acc01, 0, 0, 0);
    acc01 = __builtin_amdgcn_mfma_f32_16x16x32_bf16(ah0, bl1, acc01, 0, 0, 0);
    acc01 = __builtin_amdgcn_mfma_f32_16x16x32_bf16(al0, bh1, acc01, 0, 0, 0);
    acc10 = __builtin_amdgcn_mfma_f32_16x16x32_bf16(ah1, bh0, acc10, 0, 0, 0);
    acc10 = __builtin_amdgcn_mfma_f32_16x16x32_bf16(ah1, bl0, acc10, 0, 0, 0);
    acc10 = __builtin_amdgcn_mfma_f32_16x16x32_bf16(al1, bh0, acc10, 0, 0, 0);
    acc11 = __builtin_amdgcn_mfma_f32_16x16x32_bf16(ah1, bh1, acc11, 0, 0, 0);
    acc11 = __builtin_amdgcn_mfma_f32_16x16x32_bf16(ah1, bl1, acc11, 0, 0, 0);
    acc11 = __builtin_amdgcn_mfma_f32_16x16x32_bf16(al1, bh1, acc11, 0, 0, 0);
  }

  // epilogue: C/D layout col = lane&15, row = 4*(lane>>4) + reg [verified m89]
  f32x4 accs[2][2] = {{acc00, acc01}, {acc10, acc11}};
  int colb = bx * 64 + wn * 32 + fr;
  int rowb = by * 64 + wm * 32 + fg * 4;
#pragma unroll
  for (int i = 0; i < 2; ++i) {
#pragma unroll
    for (int j = 0; j < 2; ++j) {
      int col = colb + j * 16;
#pragma unroll
      for (int r = 0; r < 4; ++r) {
        int row = rowb + i * 16 + r;
        float v = accs[i][j][r];
        if (ep == 1) {
          v = (v + tb[(row >> 6) * D_ + col]) * ne[row];
          unsigned short hh, ll;
          split_bf16(v, hh, ll);
          entnh[(size_t)row * D_ + col] = hh;
          entnl[(size_t)row * D_ + col] = ll;
        }
        C[(size_t)row * N + col] = v;
      }
    }
  }
}

// ---------------- score[b,e,a] = dot(entity_new[b,e], arg[b,a]) / sqrt(D) ----------------
__global__ __launch_bounds__(256) void k_score(const float* __restrict__ entn,
                                               const float* __restrict__ argm,
                                               float* __restrict__ score) {
  int b = blockIdx.y, e = blockIdx.x, t = threadIdx.x;
  __shared__ float ent[D_];
  const float* er = entn + ((size_t)b * E_ + e) * D_;
  for (int d = t; d < D_; d += 256) ent[d] = er[d];
  __syncthreads();
  int wave = t >> 6, lane = t & 63;
  const float scale = 0.03608439182435161f;  // 1/sqrt(768)
  for (int a = wave; a < NA_; a += 4) {
    const float* ar = argm + ((size_t)b * NA_ + a) * D_;
    float p = 0.f;
#pragma unroll
    for (int i = 0; i < 12; i++) {
      int d = lane + 64 * i;
      p += ent[d] * ar[d];
    }
    for (int off = 32; off > 0; off >>= 1) p += __shfl_down(p, off);
    if (lane == 0) score[((size_t)b * E_ + e) * NA_ + a] = p * scale;
  }
}

// ---------------- L1 normalize over a (t2a) and over e (a2t) ----------------
__global__ void k_norm(const float* __restrict__ score, float* __restrict__ t2a,
                       float* __restrict__ a2t) {
  int b = blockIdx.x, t = threadIdx.x;
  __shared__ float s[E_ * NA_];
  __shared__ float rs[E_];
  __shared__ float cs[NA_];
  for (int i = t; i < E_ * NA_; i += 256) s[i] = score[(size_t)b * E_ * NA_ + i];
  __syncthreads();
  if (t < E_) {
    float sum = 0.f;
    for (int a = 0; a < NA_; a++) sum += fabsf(s[t * NA_ + a]);
    rs[t] = fmaxf(sum, EPSF);
  } else if (t >= 64 && t < 96) {
    int a = t - 64;
    float sum = 0.f;
    for (int e = 0; e < E_; e++) sum += fabsf(s[e * NA_ + a]);
    cs[a] = fmaxf(sum, EPSF);
  }
  __syncthreads();
  for (int i = t; i < E_ * NA_; i += 256) {
    int e = i >> 5, a = i & 31;
    float v = s[i];
    t2a[(size_t)b * E_ * NA_ + i] = v / rs[e];
    a2t[(size_t)b * E_ * NA_ + i] = v / cs[a];
  }
}

// ---------------- a2a = softmax(arg @ arg^T) ----------------
__global__ __launch_bounds__(256) void k_a2a(const float* __restrict__ argm,
                                             float* __restrict__ a2a) {
  int b = blockIdx.y, a = blockIdx.x, t = threadIdx.x;
  __shared__ float sA[D_];
  __shared__ float lg[NA_];
  const float* ar = argm + ((size_t)b * NA_ + a) * D_;
  for (int d = t; d < D_; d += 256) sA[d] = ar[d];
  __syncthreads();
  int wave = t >> 6, lane = t & 63;
  for (int a2 = wave; a2 < NA_; a2 += 4) {
    const float* br = argm + ((size_t)b * NA_ + a2) * D_;
    float p = 0.f;
#pragma unroll
    for (int i = 0; i < 12; i++) {
      int d = lane + 64 * i;
      p += sA[d] * br[d];
    }
    for (int off = 32; off > 0; off >>= 1) p += __shfl_down(p, off);
    if (lane == 0) lg[a2] = p;
  }
  __syncthreads();
  if (t < 64) {
    float v = (t < NA_) ? lg[t] : -INFINITY;
    float m = v;
    for (int mask = 16; mask > 0; mask >>= 1) m = fmaxf(m, __shfl_xor(m, mask));
    float ex = (t < NA_) ? expf(v - m) : 0.f;
    float sm = ex;
    for (int mask = 16; mask > 0; mask >>= 1) sm += __shfl_xor(sm, mask);
    if (t < NA_) a2a[((size_t)b * NA_ + a) * NA_ + t] = ex / sm;
  }
}

// ---------------- t2t: gathered, head-mean, per-att row-normalized, averaged ----------------
__global__ __launch_bounds__(128) void k_t2t(const float* __restrict__ att0,
                                             const float* __restrict__ att1,
                                             const float* __restrict__ att2,
                                             const int* __restrict__ idxs,
                                             const int* __restrict__ meta,
                                             float* __restrict__ t2t) {
  int b = blockIdx.y, s = blockIdx.x, t = threadIdx.x;
  int sb = meta[b * 4 + 0];
  float* out = t2t + ((size_t)b * S_ + s) * S_;
  if (s >= sb) {
    for (int j = t; j < S_; j += 128) out[j] = 0.f;
    return;
  }
  int Is = idxs[b * WIDX_ + s];
  int It = (t < S_) ? idxs[b * WIDX_ + t] : 0;
  __shared__ float row[256];
  __shared__ float red[128];
  const float* atts[3] = {att0, att1, att2};
  float accout = 0.f;
  for (int q = 0; q < 3; q++) {
    float r0 = 0.f, r1 = 0.f;
    const float* base = atts[q] + (((size_t)b * H_) * L_ + Is) * L_;
    for (int h = 0; h < H_; h++) {
      const float* rp = base + (size_t)h * L_ * L_;
      r0 += rp[t];
      r1 += rp[t + 128];
    }
    row[t] = r0;
    row[t + 128] = r1;
    __syncthreads();
    float v = (t < sb) ? row[It] * (1.f / 12.f) : 0.f;
    red[t] = v;
    __syncthreads();
    for (int s2 = 64; s2 > 0; s2 >>= 1) {
      if (t < s2) red[t] += red[t + s2];
      __syncthreads();
    }
    float rsum = red[0];
    __syncthreads();
    accout += v / fmaxf(rsum, EPSF) * (1.f / 3.f);
  }
  if (t < S_) out[t] = accout;
}

// ---------------- mix: ps[e] = PeA[e] + b1 + t2a[e,:]@P2 ; qs[a] = PaA[a] + a2t[:,a]@Q2 ----
__global__ __launch_bounds__(256) void k_mix(const float* __restrict__ PeA,
                                             const float* __restrict__ PaA,
                                             const float* __restrict__ P2,
                                             const float* __restrict__ Q2,
                                             const float* __restrict__ t2a,
                                             const float* __restrict__ a2t,
                                             const float* __restrict__ b1,
                                             float* __restrict__ ps, float* __restrict__ qs) {
  int b = blockIdx.y, x = blockIdx.x, t = threadIdx.x;
  int n0 = t * 4;
  __shared__ float w[E_];
  if (x < E_) {
    int e = x;
    size_t ro = ((size_t)b * E_ + e) * NHID_ + n0;
    float4 acc = *(const float4*)(PeA + ro);
    float4 bb = *(const float4*)(b1 + n0);
    acc.x += bb.x; acc.y += bb.y; acc.z += bb.z; acc.w += bb.w;
    if (t < NA_) w[t] = t2a[((size_t)b * E_ + e) * NA_ + t];
    __syncthreads();
    const float* pb = P2 + (size_t)b * NA_ * NHID_ + n0;
#pragma unroll 4
    for (int a = 0; a < NA_; a++) {
      float ww = w[a];
      float4 p = *(const float4*)(pb + (size_t)a * NHID_);
      acc.x += ww * p.x; acc.y += ww * p.y; acc.z += ww * p.z; acc.w += ww * p.w;
    }
    *(float4*)(ps + ro) = acc;
  } else {
    int a = x - E_;
    size_t ro = ((size_t)b * NA_ + a) * NHID_ + n0;
    float4 acc = *(const float4*)(PaA + ro);
    for (int i = t; i < E_; i += 256) w[i] = a2t[((size_t)b * E_ + i) * NA_ + a];
    __syncthreads();
    const float* qb = Q2 + (size_t)b * E_ * NHID_ + n0;
#pragma unroll 4
    for (int e = 0; e < E_; e++) {
      float ww = w[e];
      float4 q = *(const float4*)(qb + (size_t)e * NHID_);
      acc.x += ww * q.x; acc.y += ww * q.y; acc.z += ww * q.z; acc.w += ww * q.w;
    }
    *(float4*)(qs + ro) = acc;
  }
}

// ---------------- final: out[b,e,a] = sum_n gelu(ps[e,n]+qs[a,n]) * W2[n] + b2 ------------
__global__ __launch_bounds__(256) void k_final(const float* __restrict__ ps,
                                               const float* __restrict__ qs,
                                               const float* __restrict__ W2,
                                               const float* __restrict__ b2,
                                               float* __restrict__ out) {
  int b = blockIdx.y, e = blockIdx.x, t = threadIdx.x;
  int wave = t >> 6, lane = t & 63;
  const float ks = 0.70710678118654752f;
  size_t po = ((size_t)b * E_ + e) * NHID_ + lane * 4;
  float4 p0 = *(const float4*)(ps + po);
  float4 p1 = *(const float4*)(ps + po + 256);
  float4 p2 = *(const float4*)(ps + po + 512);
  float4 p3 = *(const float4*)(ps + po + 768);
  const float* w2p = W2 + lane * 4;
  float4 w0 = *(const float4*)(w2p);
  float4 w1 = *(const float4*)(w2p + 256);
  float4 w2 = *(const float4*)(w2p + 512);
  float4 w3 = *(const float4*)(w2p + 768);
  __shared__ float outs[NA_];
#pragma unroll 2
  for (int a = wave; a < NA_; a += 4) {
    size_t qo = ((size_t)b * NA_ + a) * NHID_ + lane * 4;
    float4 q0 = *(const float4*)(qs + qo);
    float4 q1 = *(const float4*)(qs + qo + 256);
    float4 q2 = *(const float4*)(qs + qo + 512);
    float4 q3 = *(const float4*)(qs + qo + 768);
    float acc = 0.f;
#define GEL4(pp, qq, ww)                                          \
    {                                                             \
      float x0 = pp.x + qq.x, x1 = pp.y + qq.y;                   \
      float x2 = pp.z + qq.z, x3 = pp.w + qq.w;                   \
      float g0 = 0.5f * x0 * (1.f + erff(x0 * ks));               \
      float g1 = 0.5f * x1 * (1.f + erff(x1 * ks));               \
      float g2 = 0.5f * x2 * (1.f + erff(x2 * ks));               \
      float g3 = 0.5f * x3 * (1.f + erff(x3 * ks));               \
      acc += g0 * ww.x + g1 * ww.y + g2 * ww.z + g3 * ww.w;       \
    }
    GEL4(p0, q0, w0)
    GEL4(p1, q1, w1)
    GEL4(p2, q2, w2)
    GEL4(p3, q3, w3)
#undef GEL4
    acc += __shfl_xor(acc, 32);
    acc += __shfl_xor(acc, 16);
    acc += __shfl_xor(acc, 8);
    acc += __shfl_xor(acc, 4);
    acc += __shfl_xor(acc, 2);
    acc += __shfl_xor(acc, 1);
    if (lane == 0) outs[a] = acc;
  }
  __syncthreads();
  if (t < NA_) out[((size_t)b * E_ + e) * NA_ + t] = outs[t] + b2[0];
}

extern "C" void kernel_launch(void* const* d_in, const int* in_sizes, int n_in,
                              void* d_out, int out_size, void* d_ws, size_t ws_size,
                              hipStream_t stream) {
  const float* emb    = (const float*)d_in[0];
  const float* istrig = (const float*)d_in[1];
  const float* argw   = (const float*)d_in[2];
  const float* entmap = (const float*)d_in[3];
  const float* att0   = (const float*)d_in[4];
  const float* att1   = (const float*)d_in[5];
  const float* att2   = (const float*)d_in[6];
  const float* W_ta   = (const float*)d_in[7];
  const float* b_ta   = (const float*)d_in[8];
  const float* W1     = (const float*)d_in[9];
  const float* b1     = (const float*)d_in[10];
  const float* W2     = (const float*)d_in[11];
  const float* b2     = (const float*)d_in[12];
  const int*   idxs   = (const int*)d_in[13];
  const int*   blen   = (const int*)d_in[14];
  float* out = (float*)d_out;

  float* ws = (float*)d_ws;
  size_t o = 0;
  int* meta = (int*)ws; o += 256;
  float* sent_emb = ws + o; o += (size_t)B_ * S_ * D_;   // dead after phase A -> reused as ps
  float* arg_emb  = ws + o; o += (size_t)B_ * LA_ * D_;  // dead after argm  -> reused as qs
  float* trig     = ws + o; o += (size_t)B_ * D_;
  float* argm     = ws + o; o += (size_t)B_ * NA_ * D_;
  float* entn     = ws + o; o += (size_t)B_ * E_ * D_;
  float* tb       = ws + o; o += (size_t)B_ * D_;
  float* ne       = ws + o; o += (size_t)B_ * E_;
  float* score    = ws + o; o += (size_t)B_ * E_ * NA_;
  float* t2a      = ws + o; o += (size_t)B_ * E_ * NA_;
  float* a2t      = ws + o; o += (size_t)B_ * E_ * NA_;
  float* t2t      = ws + o; o += (size_t)B_ * S_ * S_;
  float* ah2h     = ws + o; o += (size_t)B_ * S_ * D_;
  float* a2a      = ws + o; o += (size_t)B_ * NA_ * NA_;
  float* PeA      = ws + o; o += (size_t)B_ * E_ * NHID_;
  float* PaA      = ws + o; o += (size_t)B_ * NA_ * NHID_;
  float* P2       = ws + o; o += (size_t)B_ * NA_ * NHID_;
  float* Q2       = ws + o; o += (size_t)B_ * E_ * NHID_;
  float* ps = sent_emb;  // 1.05M floats <= 1.23M
  float* qs = arg_emb;   // 0.52M floats <= 0.59M

  // split-bf16 region (hi/lo pairs), 16B-aligned
  o = (o + 3) & ~(size_t)3;
  unsigned short* us = (unsigned short*)(ws + o);
  size_t uo = 0;
  unsigned short* e0h   = us + uo; uo += (size_t)B_ * E_ * D_;
  unsigned short* e0l   = us + uo; uo += (size_t)B_ * E_ * D_;
  unsigned short* e0th  = us + uo; uo += (size_t)B_ * E_ * D_;
  unsigned short* e0tl  = us + uo; uo += (size_t)B_ * E_ * D_;
  unsigned short* Ah2hh = us + uo; uo += (size_t)B_ * E_ * D_;
  unsigned short* Ah2hl = us + uo; uo += (size_t)B_ * E_ * D_;
  unsigned short* argmh = us + uo; uo += (size_t)B_ * NA_ * D_;
  unsigned short* argml = us + uo; uo += (size_t)B_ * NA_ * D_;
  unsigned short* Au2uh = us + uo; uo += (size_t)B_ * NA_ * D_;
  unsigned short* Au2ul = us + uo; uo += (size_t)B_ * NA_ * D_;
  unsigned short* entnh = us + uo; uo += (size_t)B_ * E_ * D_;
  unsigned short* entnl = us + uo; uo += (size_t)B_ * E_ * D_;
  unsigned short* WtaTh = us + uo; uo += (size_t)2304 * 768;
  unsigned short* WtaTl = us + uo; uo += (size_t)2304 * 768;
  unsigned short* W1Th  = us + uo; uo += (size_t)4608 * 1024;
  unsigned short* W1Tl  = us + uo; uo += (size_t)4608 * 1024;

  // ---- phase A: gathers + weight transpose/split + everything not needing entity_new ----
  k_meta<<<B_, 128, 0, stream>>>(idxs, blen, meta);
  k_cvtT<<<dim3(2304 / 32, 768 / 32), 256, 0, stream>>>(W_ta, 2304, 768, WtaTh, WtaTl);
  k_cvtT<<<dim3(4608 / 32, 1024 / 32), 256, 0, stream>>>(W1, 4608, 1024, W1Th, W1Tl);
  k_gather<<<dim3(S_ + LA_, B_), 256, 0, stream>>>(emb, idxs, meta, sent_emb, arg_emb);
  k_trig<<<dim3(3, B_), 256, 0, stream>>>(sent_emb, istrig, trig);
  k_entity0<<<dim3(E_, B_), 256, 0, stream>>>(sent_emb, entmap, trig, e0h, e0l, e0th, e0tl, ne);
  k_wsum<<<dim3(NA_, B_), 256, 0, stream>>>(argw, LA_ * NA_, NA_, 1, arg_emb, argm, argmh,
                                            argml, LA_);
  k_tb<<<dim3(3, B_), 256, 0, stream>>>(trig, W_ta, b_ta, tb);
  k_t2t<<<dim3(S_, B_), 128, 0, stream>>>(att0, att1, att2, idxs, meta, t2t);
  k_wsum<<<dim3(S_, B_), 256, 0, stream>>>(t2t, S_ * S_, 1, S_, sent_emb, ah2h, nullptr,
                                           nullptr, S_);
  k_wsum<<<dim3(E_, B_), 256, 0, stream>>>(entmap, S_ * E_, E_, 1, ah2h, nullptr, Ah2hh,
                                           Ah2hl, S_);
  k_a2a<<<dim3(NA_, B_), 256, 0, stream>>>(argm, a2a);
  k_wsum<<<dim3(NA_, B_), 256, 0, stream>>>(a2a, NA_ * NA_, 1, NA_, argm, nullptr, Au2uh,
                                            Au2ul, NA_);

  // ---- phase B: entn (fused ep + split), PeA, PaA, P2 — one launch, z=0..3 ----
  k_mgemm<<<dim3(16, 16, 4), 256, 0, stream>>>(0, e0h, e0l, e0th, e0tl, Ah2hh, Ah2hl, argmh,
                                               argml, Au2uh, Au2ul, WtaTh, WtaTl, W1Th, W1Tl,
                                               entn, entnh, entnl, PeA, PaA, P2, Q2, tb, ne);

  // ---- Q2 = entn@W1[4] ----
  k_mgemm<<<dim3(16, 16, 1), 256, 0, stream>>>(1, e0h, e0l, e0th, e0tl, Ah2hh, Ah2hl, argmh,
                                               argml, Au2uh, Au2ul, WtaTh, WtaTl, W1Th, W1Tl,
                                               entn, entnh, entnl, PeA, PaA, P2, Q2, tb, ne);

  // ---- phase C: score path ----
  k_score<<<dim3(E_, B_), 256, 0, stream>>>(entn, argm, score);
  k_norm<<<B_, 256, 0, stream>>>(score, t2a, a2t);
  k_mix<<<dim3(E_ + NA_, B_), 256, 0, stream>>>(PeA, PaA, P2, Q2, t2a, a2t, b1, ps, qs);

  // ---- final ----
  k_final<<<dim3(E_, B_), 256, 0, stream>>>(ps, qs, W2, b2, out);
}